// Round 1
// baseline (4352.913 us; speedup 1.0000x reference)
//
#include <hip/hip_runtime.h>

#define D 64           // feature dim (in == out == 64 per reference)
#define BLK 256

// ---------------- degree: deg[row[e]] += 1 ----------------
__global__ void deg_kernel(const int* __restrict__ row, float* __restrict__ deg, int E) {
    int e = blockIdx.x * BLK + threadIdx.x;
    if (e < E) atomicAdd(&deg[row[e]], 1.0f);
}

// ---------------- dinv[n] = deg>0 ? deg^-0.5 : 0 ----------------
__global__ void dinv_kernel(const float* __restrict__ deg, float* __restrict__ dinv, int N) {
    int n = blockIdx.x * BLK + threadIdx.x;
    if (n < N) {
        float d = deg[n];
        dinv[n] = (d > 0.0f) ? rsqrtf(d) : 0.0f;
    }
}

// ---------------- lap[e] = -dinv[row]*attr*dinv[col] ----------------
__global__ void lap_kernel(const int* __restrict__ row, const int* __restrict__ col,
                           const float* __restrict__ attr, const float* __restrict__ dinv,
                           float* __restrict__ lap, int E) {
    int e = blockIdx.x * BLK + threadIdx.x;
    if (e < E) lap[e] = -dinv[row[e]] * attr[e] * dinv[col[e]];
}

// ---------------- dst = -src (float4), used to fold "2*spmm - prev" init ----------------
__global__ void neg_kernel(float* __restrict__ dst, const float* __restrict__ src, int n4) {
    int i = blockIdx.x * BLK + threadIdx.x;
    if (i < n4) {
        float4 v = ((const float4*)src)[i];
        ((float4*)dst)[i] = make_float4(-v.x, -v.y, -v.z, -v.w);
    }
}

// ---------------- spmm: out[row[e]] += scale*lap[e]*h[col[e]]  (16 lanes / edge) ----------------
__global__ void spmm_kernel(const int* __restrict__ row, const int* __restrict__ col,
                            const float* __restrict__ lap, const float* __restrict__ h,
                            float* __restrict__ out, float scale, int E) {
    int gid = blockIdx.x * BLK + threadIdx.x;
    int e = gid >> 4;
    if (e >= E) return;
    int c = (gid & 15) * 4;
    float l = scale * lap[e];
    int cn = col[e];
    int rn = row[e];
    float4 hv = *(const float4*)&h[(size_t)cn * D + c];
    float* o = &out[(size_t)rn * D + c];
    atomicAdd(o + 0, l * hv.x);
    atomicAdd(o + 1, l * hv.y);
    atomicAdd(o + 2, l * hv.z);
    atomicAdd(o + 3, l * hv.w);
}

// ---------------- gemm: out[n,:] (=bias) + sum_k h_k[n,:] @ W_k, W staged in LDS ----------------
// nk in {1,2}; accumulate: read-modify-write out; else out = bias + ...
__global__ void gemm_acc_kernel(const float* __restrict__ h0, const float* __restrict__ h1,
                                const float* __restrict__ W,   // nk contiguous 64x64 row-major
                                const float* __restrict__ bias,
                                float* __restrict__ out, int N, int nk, int accumulate) {
    __shared__ float Ws[2 * D * D];
    int tid = threadIdx.x;
    int nload = nk * D * D;
    for (int i = tid * 4; i < nload; i += BLK * 4)
        *(float4*)&Ws[i] = *(const float4*)&W[i];
    __syncthreads();

    int n = blockIdx.x * 16 + (tid >> 4);
    if (n >= N) return;
    int c = (tid & 15) * 4;

    float4 acc;
    if (accumulate) {
        acc = *(float4*)&out[(size_t)n * D + c];
    } else {
        acc = make_float4(bias[c], bias[c + 1], bias[c + 2], bias[c + 3]);
    }

    const float* hs[2] = { h0, h1 };
    for (int k = 0; k < nk; ++k) {
        const float* h = hs[k] + (size_t)n * D;
        const float* Wk = &Ws[k * D * D];
        #pragma unroll
        for (int i4 = 0; i4 < 16; ++i4) {
            float4 hv = *(const float4*)&h[i4 * 4];
            #pragma unroll
            for (int u = 0; u < 4; ++u) {
                float hsv = (u == 0) ? hv.x : (u == 1) ? hv.y : (u == 2) ? hv.z : hv.w;
                float4 wv = *(const float4*)&Wk[(i4 * 4 + u) * D + c];
                acc.x += hsv * wv.x;
                acc.y += hsv * wv.y;
                acc.z += hsv * wv.z;
                acc.w += hsv * wv.w;
            }
        }
    }
    *(float4*)&out[(size_t)n * D + c] = acc;
}

extern "C" void kernel_launch(void* const* d_in, const int* in_sizes, int n_in,
                              void* d_out, int out_size, void* d_ws, size_t ws_size,
                              hipStream_t stream) {
    const float* x    = (const float*)d_in[0];
    const int*   ei   = (const int*)d_in[1];
    const float* attr = (const float*)d_in[2];
    const float* W    = (const float*)d_in[3];   // [4,64,64]
    const float* bias = (const float*)d_in[4];   // [64]
    float* out = (float*)d_out;

    const int N = in_sizes[0] / D;
    const int E = in_sizes[1] / 2;
    const int* row = ei;        // edge_index[0]
    const int* col = ei + E;    // edge_index[1]

    float* ws   = (float*)d_ws;
    float* deg  = ws;                       // N
    float* dinv = ws + N;                   // N
    float* lap  = ws + 2 * (size_t)N;       // E
    float* T1   = lap + E;                  // N*64
    float* T2   = T1 + (size_t)N * D;       // N*64

    const int gE   = (E + BLK - 1) / BLK;
    const int gN   = (N + BLK - 1) / BLK;
    const int gSp  = (E * 16 + BLK - 1) / BLK;
    const int gNeg = ((N * D / 4) + BLK - 1) / BLK;
    const int gGe  = (N + 15) / 16;

    // degree -> dinv -> lap
    hipMemsetAsync(deg, 0, (size_t)N * sizeof(float), stream);
    deg_kernel<<<gE, BLK, 0, stream>>>(row, deg, E);
    dinv_kernel<<<gN, BLK, 0, stream>>>(deg, dinv, N);
    lap_kernel<<<gE, BLK, 0, stream>>>(row, col, attr, dinv, lap, E);

    // tx1 = spmm(x)
    hipMemsetAsync(T1, 0, (size_t)N * D * sizeof(float), stream);
    spmm_kernel<<<gSp, BLK, 0, stream>>>(row, col, lap, x, T1, 1.0f, E);

    // out = bias + x@W0 + tx1@W1
    gemm_acc_kernel<<<gGe, BLK, 0, stream>>>(x, T1, W, bias, out, N, 2, 0);

    // tx2 = 2*spmm(tx1) - x   (init T2 = -x, spmm adds 2*lap*tx1)
    neg_kernel<<<gNeg, BLK, 0, stream>>>(T2, x, N * D / 4);
    spmm_kernel<<<gSp, BLK, 0, stream>>>(row, col, lap, T1, T2, 2.0f, E);
    gemm_acc_kernel<<<gGe, BLK, 0, stream>>>(T2, nullptr, W + 2 * D * D, nullptr, out, N, 1, 1);

    // tx3 = 2*spmm(tx2) - tx1  (negate T1 in place, spmm adds into it)
    neg_kernel<<<gNeg, BLK, 0, stream>>>(T1, T1, N * D / 4);
    spmm_kernel<<<gSp, BLK, 0, stream>>>(row, col, lap, T2, T1, 2.0f, E);
    gemm_acc_kernel<<<gGe, BLK, 0, stream>>>(T1, nullptr, W + 3 * D * D, nullptr, out, N, 1, 1);
}

// Round 2
// 628.893 us; speedup vs baseline: 6.9215x; 6.9215x over previous
//
#include <hip/hip_runtime.h>

#define D 64
#define BLK 256
#define SCAN_T 256
#define SCAN_E 8           // elements per thread in scan_a
#define SCAN_CHUNK (SCAN_T * SCAN_E)   // 2048 per block

typedef unsigned int uint32;

// ---------------- histogram: deg[row[e]] += 1 ----------------
__global__ void deg_kernel(const int* __restrict__ row, uint32* __restrict__ deg, int E) {
    int e = blockIdx.x * BLK + threadIdx.x;
    if (e < E) atomicAdd(&deg[row[e]], 1u);
}

// ---------------- dinv[n] = deg>0 ? deg^-0.5 : 0 ----------------
__global__ void dinv_kernel(const uint32* __restrict__ deg, float* __restrict__ dinv, int N) {
    int n = blockIdx.x * BLK + threadIdx.x;
    if (n < N) {
        uint32 d = deg[n];
        dinv[n] = (d > 0u) ? rsqrtf((float)d) : 0.0f;
    }
}

// ---------------- scan A: per-block exclusive scan of deg -> rowptr, block totals -> partials ----------------
__global__ void scan_a_kernel(const uint32* __restrict__ deg, uint32* __restrict__ rowptr,
                              uint32* __restrict__ partials, int N) {
    __shared__ uint32 sums[SCAN_T];
    int tid = threadIdx.x;
    int base = blockIdx.x * SCAN_CHUNK + tid * SCAN_E;
    uint32 v[SCAN_E];
    uint32 s = 0;
    #pragma unroll
    for (int i = 0; i < SCAN_E; ++i) {
        uint32 d = (base + i < N) ? deg[base + i] : 0u;
        v[i] = s;
        s += d;
    }
    sums[tid] = s;
    __syncthreads();
    // Hillis-Steele inclusive scan in LDS
    for (int off = 1; off < SCAN_T; off <<= 1) {
        uint32 t = (tid >= off) ? sums[tid - off] : 0u;
        __syncthreads();
        sums[tid] += t;
        __syncthreads();
    }
    uint32 excl = (tid > 0) ? sums[tid - 1] : 0u;
    #pragma unroll
    for (int i = 0; i < SCAN_E; ++i) {
        if (base + i < N) rowptr[base + i] = excl + v[i];
    }
    if (tid == SCAN_T - 1) partials[blockIdx.x] = sums[SCAN_T - 1];
}

// ---------------- scan B: exclusive scan of block partials (single block) ----------------
__global__ void scan_b_kernel(uint32* __restrict__ partials, int nblk) {
    __shared__ uint32 buf[256];
    int tid = threadIdx.x;
    if (tid < nblk) buf[tid] = partials[tid];
    __syncthreads();
    if (tid == 0) {
        uint32 run = 0;
        for (int i = 0; i < nblk; ++i) { uint32 t = buf[i]; buf[i] = run; run += t; }
    }
    __syncthreads();
    if (tid < nblk) partials[tid] = buf[tid];
}

// ---------------- scan C: add block offsets; init cursor; set rowptr[N] ----------------
__global__ void scan_c_kernel(uint32* __restrict__ rowptr, const uint32* __restrict__ partials,
                              uint32* __restrict__ cursor, int N, int E) {
    int i = blockIdx.x * BLK + threadIdx.x;
    if (i < N) {
        uint32 r = rowptr[i] + partials[i / SCAN_CHUNK];
        rowptr[i] = r;
        cursor[i] = r;
    }
    if (i == 0) rowptr[N] = (uint32)E;
}

// ---------------- scatter: counting-sort edges by row; compute lap on the fly ----------------
__global__ void scatter_kernel(const int* __restrict__ row, const int* __restrict__ col,
                               const float* __restrict__ attr, const float* __restrict__ dinv,
                               uint32* __restrict__ cursor,
                               int* __restrict__ col_s, float* __restrict__ lap_s, int E) {
    int e = blockIdx.x * BLK + threadIdx.x;
    if (e >= E) return;
    int r = row[e];
    int c = col[e];
    float l = -dinv[r] * attr[e] * dinv[c];
    uint32 pos = atomicAdd(&cursor[r], 1u);
    col_s[pos] = c;
    lap_s[pos] = l;
}

// ---------------- CSR SpMM: out[n,:] = scale * sum_j lap_s[j]*h[col_s[j],:]  (- prev[n,:]) ----------------
// One 64-lane wave per node, lane = feature column. No atomics.
__global__ void spmm_csr_kernel(const uint32* __restrict__ rowptr, const int* __restrict__ col_s,
                                const float* __restrict__ lap_s, const float* __restrict__ h,
                                const float* __restrict__ prev, float* __restrict__ out,
                                float scale, int N) {
    int n = blockIdx.x * (BLK / 64) + (threadIdx.x >> 6);
    if (n >= N) return;
    int lane = threadIdx.x & 63;
    uint32 j = rowptr[n];
    uint32 end = rowptr[n + 1];
    float acc = 0.0f;
    // unroll by 4 for memory-level parallelism
    for (; j + 4 <= end; j += 4) {
        float l0 = lap_s[j + 0], l1 = lap_s[j + 1], l2 = lap_s[j + 2], l3 = lap_s[j + 3];
        int c0 = col_s[j + 0], c1 = col_s[j + 1], c2 = col_s[j + 2], c3 = col_s[j + 3];
        float h0 = h[(size_t)c0 * D + lane];
        float h1 = h[(size_t)c1 * D + lane];
        float h2 = h[(size_t)c2 * D + lane];
        float h3 = h[(size_t)c3 * D + lane];
        acc += l0 * h0 + l1 * h1 + l2 * h2 + l3 * h3;
    }
    for (; j < end; ++j) {
        acc += lap_s[j] * h[(size_t)col_s[j] * D + lane];
    }
    float r = scale * acc;
    if (prev) r -= prev[(size_t)n * D + lane];
    out[(size_t)n * D + lane] = r;
}

// ---------------- gemm: out[n,:] = (bias or out) + sum_k h_k[n,:] @ W_k ----------------
__global__ void gemm_acc_kernel(const float* __restrict__ h0, const float* __restrict__ h1,
                                const float* __restrict__ W, const float* __restrict__ bias,
                                float* __restrict__ out, int N, int nk, int accumulate) {
    __shared__ float Ws[2 * D * D];
    int tid = threadIdx.x;
    int nload = nk * D * D;
    for (int i = tid * 4; i < nload; i += BLK * 4)
        *(float4*)&Ws[i] = *(const float4*)&W[i];
    __syncthreads();

    int n = blockIdx.x * 16 + (tid >> 4);
    if (n >= N) return;
    int c = (tid & 15) * 4;

    float4 acc;
    if (accumulate) {
        acc = *(float4*)&out[(size_t)n * D + c];
    } else {
        acc = make_float4(bias[c], bias[c + 1], bias[c + 2], bias[c + 3]);
    }

    const float* hs[2] = { h0, h1 };
    for (int k = 0; k < nk; ++k) {
        const float* h = hs[k] + (size_t)n * D;
        const float* Wk = &Ws[k * D * D];
        #pragma unroll
        for (int i4 = 0; i4 < 16; ++i4) {
            float4 hv = *(const float4*)&h[i4 * 4];
            #pragma unroll
            for (int u = 0; u < 4; ++u) {
                float hsv = (u == 0) ? hv.x : (u == 1) ? hv.y : (u == 2) ? hv.z : hv.w;
                float4 wv = *(const float4*)&Wk[(i4 * 4 + u) * D + c];
                acc.x += hsv * wv.x;
                acc.y += hsv * wv.y;
                acc.z += hsv * wv.z;
                acc.w += hsv * wv.w;
            }
        }
    }
    *(float4*)&out[(size_t)n * D + c] = acc;
}

extern "C" void kernel_launch(void* const* d_in, const int* in_sizes, int n_in,
                              void* d_out, int out_size, void* d_ws, size_t ws_size,
                              hipStream_t stream) {
    const float* x    = (const float*)d_in[0];
    const int*   ei   = (const int*)d_in[1];
    const float* attr = (const float*)d_in[2];
    const float* W    = (const float*)d_in[3];   // [4,64,64]
    const float* bias = (const float*)d_in[4];   // [64]
    float* out = (float*)d_out;

    const int N = in_sizes[0] / D;
    const int E = in_sizes[1] / 2;
    const int* row = ei;        // edge_index[0]
    const int* col = ei + E;    // edge_index[1]

    // workspace layout
    char* p = (char*)d_ws;
    uint32* deg     = (uint32*)p;                p += (size_t)N * 4;
    uint32* rowptr  = (uint32*)p;                p += (size_t)(N + 1) * 4;
    uint32* cursor  = (uint32*)p;                p += (size_t)N * 4;
    uint32* partials= (uint32*)p;                p += 256 * 4;
    float*  dinv    = (float*)p;                 p += (size_t)N * 4;
    int*    col_s   = (int*)p;                   p += (size_t)E * 4;
    float*  lap_s   = (float*)p;                 p += (size_t)E * 4;
    float*  T1      = (float*)p;                 p += (size_t)N * D * 4;
    float*  T2      = (float*)p;                 /* p += N*D*4 */

    const int gE  = (E + BLK - 1) / BLK;
    const int gN  = (N + BLK - 1) / BLK;
    const int nScanBlk = (N + SCAN_CHUNK - 1) / SCAN_CHUNK;
    const int gSp = (N + (BLK / 64) - 1) / (BLK / 64);
    const int gGe = (N + 15) / 16;

    // ---- build CSR (counting sort by row) + dinv ----
    hipMemsetAsync(deg, 0, (size_t)N * 4, stream);
    deg_kernel<<<gE, BLK, 0, stream>>>(row, deg, E);
    dinv_kernel<<<gN, BLK, 0, stream>>>(deg, dinv, N);
    scan_a_kernel<<<nScanBlk, SCAN_T, 0, stream>>>(deg, rowptr, partials, N);
    scan_b_kernel<<<1, 256, 0, stream>>>(partials, nScanBlk);
    scan_c_kernel<<<gN, BLK, 0, stream>>>(rowptr, partials, cursor, N, E);
    scatter_kernel<<<gE, BLK, 0, stream>>>(row, col, attr, dinv, cursor, col_s, lap_s, E);

    // ---- Chebyshev recurrence ----
    // T1 = spmm(x)
    spmm_csr_kernel<<<gSp, BLK, 0, stream>>>(rowptr, col_s, lap_s, x, nullptr, T1, 1.0f, N);
    // out = bias + x@W0 + T1@W1
    gemm_acc_kernel<<<gGe, BLK, 0, stream>>>(x, T1, W, bias, out, N, 2, 0);
    // T2 = 2*spmm(T1) - x
    spmm_csr_kernel<<<gSp, BLK, 0, stream>>>(rowptr, col_s, lap_s, T1, x, T2, 2.0f, N);
    gemm_acc_kernel<<<gGe, BLK, 0, stream>>>(T2, nullptr, W + 2 * D * D, nullptr, out, N, 1, 1);
    // T1' = 2*spmm(T2) - T1   (write into T1's storage is unsafe: T1 is an input; use separate? )
    // T1 is read as 'prev' and as gemm input h already consumed; spmm reads h=T2, prev=T1, writes T1 -> RAW ok per element:
    // each (n,lane) reads prev[n,lane] then writes out[n,lane]; h=T2 untouched. Writing T1 in place is safe
    // because spmm only reads T1 at the same (n,lane) it writes, and h reads come from T2 only.
    spmm_csr_kernel<<<gSp, BLK, 0, stream>>>(rowptr, col_s, lap_s, T2, T1, T1, 2.0f, N);
    gemm_acc_kernel<<<gGe, BLK, 0, stream>>>(T1, nullptr, W + 3 * D * D, nullptr, out, N, 1, 1);
}

// Round 3
// 574.482 us; speedup vs baseline: 7.5771x; 1.0947x over previous
//
#include <hip/hip_runtime.h>

#define D 64
#define BLK 256
#define SCAN_T 256
#define SCAN_E 8           // elements per thread in scan_a
#define SCAN_CHUNK (SCAN_T * SCAN_E)   // 2048 per block

typedef unsigned int uint32;

// ---------------- histogram: deg[row[e]] += 1 ----------------
__global__ void deg_kernel(const int* __restrict__ row, uint32* __restrict__ deg, int E) {
    int e = blockIdx.x * BLK + threadIdx.x;
    if (e < E) atomicAdd(&deg[row[e]], 1u);
}

// ---------------- dinv[n] = deg>0 ? deg^-0.5 : 0 ----------------
__global__ void dinv_kernel(const uint32* __restrict__ deg, float* __restrict__ dinv, int N) {
    int n = blockIdx.x * BLK + threadIdx.x;
    if (n < N) {
        uint32 d = deg[n];
        dinv[n] = (d > 0u) ? rsqrtf((float)d) : 0.0f;
    }
}

// ---------------- scan A: per-block exclusive scan of deg -> rowptr, block totals -> partials ----------------
__global__ void scan_a_kernel(const uint32* __restrict__ deg, uint32* __restrict__ rowptr,
                              uint32* __restrict__ partials, int N) {
    __shared__ uint32 sums[SCAN_T];
    int tid = threadIdx.x;
    int base = blockIdx.x * SCAN_CHUNK + tid * SCAN_E;
    uint32 v[SCAN_E];
    uint32 s = 0;
    #pragma unroll
    for (int i = 0; i < SCAN_E; ++i) {
        uint32 d = (base + i < N) ? deg[base + i] : 0u;
        v[i] = s;
        s += d;
    }
    sums[tid] = s;
    __syncthreads();
    for (int off = 1; off < SCAN_T; off <<= 1) {
        uint32 t = (tid >= off) ? sums[tid - off] : 0u;
        __syncthreads();
        sums[tid] += t;
        __syncthreads();
    }
    uint32 excl = (tid > 0) ? sums[tid - 1] : 0u;
    #pragma unroll
    for (int i = 0; i < SCAN_E; ++i) {
        if (base + i < N) rowptr[base + i] = excl + v[i];
    }
    if (tid == SCAN_T - 1) partials[blockIdx.x] = sums[SCAN_T - 1];
}

// ---------------- scan B: exclusive scan of block partials (single block) ----------------
__global__ void scan_b_kernel(uint32* __restrict__ partials, int nblk) {
    __shared__ uint32 buf[256];
    int tid = threadIdx.x;
    if (tid < nblk) buf[tid] = partials[tid];
    __syncthreads();
    if (tid == 0) {
        uint32 run = 0;
        for (int i = 0; i < nblk; ++i) { uint32 t = buf[i]; buf[i] = run; run += t; }
    }
    __syncthreads();
    if (tid < nblk) partials[tid] = buf[tid];
}

// ---------------- scan C: add block offsets; init cursor; set rowptr[N] ----------------
__global__ void scan_c_kernel(uint32* __restrict__ rowptr, const uint32* __restrict__ partials,
                              uint32* __restrict__ cursor, int N, int E) {
    int i = blockIdx.x * BLK + threadIdx.x;
    if (i < N) {
        uint32 r = rowptr[i] + partials[i / SCAN_CHUNK];
        rowptr[i] = r;
        cursor[i] = r;
    }
    if (i == 0) rowptr[N] = (uint32)E;
}

// ---------------- scatter: counting-sort edges by row; pack (col, lap) into one 8B store ----------------
__global__ void scatter_kernel(const int* __restrict__ row, const int* __restrict__ col,
                               const float* __restrict__ attr, const float* __restrict__ dinv,
                               uint32* __restrict__ cursor, int2* __restrict__ pairs, int E) {
    int e = blockIdx.x * BLK + threadIdx.x;
    if (e >= E) return;
    int r = row[e];
    int c = col[e];
    float l = -dinv[r] * attr[e] * dinv[c];
    uint32 pos = atomicAdd(&cursor[r], 1u);
    int2 pr;
    pr.x = c;
    pr.y = __float_as_int(l);
    pairs[pos] = pr;
}

// ---------------- CSR SpMM: out[n,:] = scale * sum_j lap[j]*h[col[j],:]  (- prev[n,:]) ----------------
// One 64-lane wave per node, lane = feature column. Unroll 8 for MLP.
__global__ void spmm_csr_kernel(const uint32* __restrict__ rowptr, const int2* __restrict__ pairs,
                                const float* __restrict__ h, const float* __restrict__ prev,
                                float* __restrict__ out, float scale, int N) {
    int n = blockIdx.x * (BLK / 64) + (threadIdx.x >> 6);
    if (n >= N) return;
    int lane = threadIdx.x & 63;
    uint32 j = rowptr[n];
    uint32 end = rowptr[n + 1];
    float acc = 0.0f;
    for (; j + 8 <= end; j += 8) {
        int2 p0 = pairs[j + 0], p1 = pairs[j + 1], p2 = pairs[j + 2], p3 = pairs[j + 3];
        int2 p4 = pairs[j + 4], p5 = pairs[j + 5], p6 = pairs[j + 6], p7 = pairs[j + 7];
        float v0 = h[(size_t)p0.x * D + lane];
        float v1 = h[(size_t)p1.x * D + lane];
        float v2 = h[(size_t)p2.x * D + lane];
        float v3 = h[(size_t)p3.x * D + lane];
        float v4 = h[(size_t)p4.x * D + lane];
        float v5 = h[(size_t)p5.x * D + lane];
        float v6 = h[(size_t)p6.x * D + lane];
        float v7 = h[(size_t)p7.x * D + lane];
        acc += __int_as_float(p0.y) * v0 + __int_as_float(p1.y) * v1
             + __int_as_float(p2.y) * v2 + __int_as_float(p3.y) * v3
             + __int_as_float(p4.y) * v4 + __int_as_float(p5.y) * v5
             + __int_as_float(p6.y) * v6 + __int_as_float(p7.y) * v7;
    }
    for (; j < end; ++j) {
        int2 p = pairs[j];
        acc += __int_as_float(p.y) * h[(size_t)p.x * D + lane];
    }
    float r = scale * acc;
    if (prev) r -= prev[(size_t)n * D + lane];
    out[(size_t)n * D + lane] = r;
}

// ---------------- gemm: out[n,:] = (bias or out) + sum_k h_k[n,:] @ W_k ----------------
__global__ void gemm_acc_kernel(const float* __restrict__ h0, const float* __restrict__ h1,
                                const float* __restrict__ W, const float* __restrict__ bias,
                                float* __restrict__ out, int N, int nk, int accumulate) {
    __shared__ float Ws[2 * D * D];
    int tid = threadIdx.x;
    int nload = nk * D * D;
    for (int i = tid * 4; i < nload; i += BLK * 4)
        *(float4*)&Ws[i] = *(const float4*)&W[i];
    __syncthreads();

    int n = blockIdx.x * 16 + (tid >> 4);
    if (n >= N) return;
    int c = (tid & 15) * 4;

    float4 acc;
    if (accumulate) {
        acc = *(float4*)&out[(size_t)n * D + c];
    } else {
        acc = make_float4(bias[c], bias[c + 1], bias[c + 2], bias[c + 3]);
    }

    const float* hs[2] = { h0, h1 };
    for (int k = 0; k < nk; ++k) {
        const float* h = hs[k] + (size_t)n * D;
        const float* Wk = &Ws[k * D * D];
        #pragma unroll
        for (int i4 = 0; i4 < 16; ++i4) {
            float4 hv = *(const float4*)&h[i4 * 4];
            #pragma unroll
            for (int u = 0; u < 4; ++u) {
                float hsv = (u == 0) ? hv.x : (u == 1) ? hv.y : (u == 2) ? hv.z : hv.w;
                float4 wv = *(const float4*)&Wk[(i4 * 4 + u) * D + c];
                acc.x += hsv * wv.x;
                acc.y += hsv * wv.y;
                acc.z += hsv * wv.z;
                acc.w += hsv * wv.w;
            }
        }
    }
    *(float4*)&out[(size_t)n * D + c] = acc;
}

extern "C" void kernel_launch(void* const* d_in, const int* in_sizes, int n_in,
                              void* d_out, int out_size, void* d_ws, size_t ws_size,
                              hipStream_t stream) {
    const float* x    = (const float*)d_in[0];
    const int*   ei   = (const int*)d_in[1];
    const float* attr = (const float*)d_in[2];
    const float* W    = (const float*)d_in[3];   // [4,64,64]
    const float* bias = (const float*)d_in[4];   // [64]
    float* out = (float*)d_out;

    const int N = in_sizes[0] / D;
    const int E = in_sizes[1] / 2;
    const int* row = ei;        // edge_index[0]
    const int* col = ei + E;    // edge_index[1]

    // workspace layout — 8B-aligned arrays first
    char* p = (char*)d_ws;
    int2*   pairs   = (int2*)p;                  p += (size_t)E * 8;
    float*  T1      = (float*)p;                 p += (size_t)N * D * 4;
    float*  T2      = (float*)p;                 p += (size_t)N * D * 4;
    uint32* deg     = (uint32*)p;                p += (size_t)N * 4;
    uint32* rowptr  = (uint32*)p;                p += (size_t)(N + 1) * 4;
    uint32* cursor  = (uint32*)p;                p += (size_t)N * 4;
    uint32* partials= (uint32*)p;                p += 256 * 4;
    float*  dinv    = (float*)p;                 /* p += N*4 */

    const int gE  = (E + BLK - 1) / BLK;
    const int gN  = (N + BLK - 1) / BLK;
    const int nScanBlk = (N + SCAN_CHUNK - 1) / SCAN_CHUNK;
    const int gSp = (N + (BLK / 64) - 1) / (BLK / 64);
    const int gGe = (N + 15) / 16;

    // ---- build CSR (counting sort by row) + dinv ----
    hipMemsetAsync(deg, 0, (size_t)N * 4, stream);
    deg_kernel<<<gE, BLK, 0, stream>>>(row, deg, E);
    dinv_kernel<<<gN, BLK, 0, stream>>>(deg, dinv, N);
    scan_a_kernel<<<nScanBlk, SCAN_T, 0, stream>>>(deg, rowptr, partials, N);
    scan_b_kernel<<<1, 256, 0, stream>>>(partials, nScanBlk);
    scan_c_kernel<<<gN, BLK, 0, stream>>>(rowptr, partials, cursor, N, E);
    scatter_kernel<<<gE, BLK, 0, stream>>>(row, col, attr, dinv, cursor, pairs, E);

    // ---- Chebyshev recurrence ----
    // T1 = spmm(x)
    spmm_csr_kernel<<<gSp, BLK, 0, stream>>>(rowptr, pairs, x, nullptr, T1, 1.0f, N);
    // out = bias + x@W0 + T1@W1
    gemm_acc_kernel<<<gGe, BLK, 0, stream>>>(x, T1, W, bias, out, N, 2, 0);
    // T2 = 2*spmm(T1) - x
    spmm_csr_kernel<<<gSp, BLK, 0, stream>>>(rowptr, pairs, T1, x, T2, 2.0f, N);
    // T1' = 2*spmm(T2) - T1  (in place: each (n,lane) reads prev[n,lane] then writes same slot; h=T2)
    spmm_csr_kernel<<<gSp, BLK, 0, stream>>>(rowptr, pairs, T2, T1, T1, 2.0f, N);
    // out += T2@W2 + T1'@W3
    gemm_acc_kernel<<<gGe, BLK, 0, stream>>>(T2, T1, W + 2 * D * D, nullptr, out, N, 2, 1);
}

// Round 4
// 550.069 us; speedup vs baseline: 7.9134x; 1.0444x over previous
//
#include <hip/hip_runtime.h>

#define D 64
#define BLK 256
#define SCAN_T 256
#define SCAN_E 8
#define SCAN_CHUNK (SCAN_T * SCAN_E)   // 2048 per block

#define NBSHIFT 9
#define NODES_PER_BKT 512              // bucket = row >> 9; NB <= 256 for N <= 131072
#define TA 4096                        // edges per binA tile

typedef unsigned int uint32;

// ---------------- histogram: deg[row[e]] += 1 ----------------
__global__ void deg_kernel(const int* __restrict__ row, uint32* __restrict__ deg, int E) {
    int e = blockIdx.x * BLK + threadIdx.x;
    if (e < E) atomicAdd(&deg[row[e]], 1u);
}

// ---------------- dinv[n] = deg>0 ? deg^-0.5 : 0 ----------------
__global__ void dinv_kernel(const uint32* __restrict__ deg, float* __restrict__ dinv, int N) {
    int n = blockIdx.x * BLK + threadIdx.x;
    if (n < N) {
        uint32 d = deg[n];
        dinv[n] = (d > 0u) ? rsqrtf((float)d) : 0.0f;
    }
}

// ---------------- scan A: per-block exclusive scan of deg -> rowptr ----------------
__global__ void scan_a_kernel(const uint32* __restrict__ deg, uint32* __restrict__ rowptr,
                              uint32* __restrict__ partials, int N) {
    __shared__ uint32 sums[SCAN_T];
    int tid = threadIdx.x;
    int base = blockIdx.x * SCAN_CHUNK + tid * SCAN_E;
    uint32 v[SCAN_E];
    uint32 s = 0;
    #pragma unroll
    for (int i = 0; i < SCAN_E; ++i) {
        uint32 d = (base + i < N) ? deg[base + i] : 0u;
        v[i] = s;
        s += d;
    }
    sums[tid] = s;
    __syncthreads();
    for (int off = 1; off < SCAN_T; off <<= 1) {
        uint32 t = (tid >= off) ? sums[tid - off] : 0u;
        __syncthreads();
        sums[tid] += t;
        __syncthreads();
    }
    uint32 excl = (tid > 0) ? sums[tid - 1] : 0u;
    #pragma unroll
    for (int i = 0; i < SCAN_E; ++i) {
        if (base + i < N) rowptr[base + i] = excl + v[i];
    }
    if (tid == SCAN_T - 1) partials[blockIdx.x] = sums[SCAN_T - 1];
}

__global__ void scan_b_kernel(uint32* __restrict__ partials, int nblk) {
    __shared__ uint32 buf[256];
    int tid = threadIdx.x;
    if (tid < nblk) buf[tid] = partials[tid];
    __syncthreads();
    if (tid == 0) {
        uint32 run = 0;
        for (int i = 0; i < nblk; ++i) { uint32 t = buf[i]; buf[i] = run; run += t; }
    }
    __syncthreads();
    if (tid < nblk) partials[tid] = buf[tid];
}

__global__ void scan_c_kernel(uint32* __restrict__ rowptr, const uint32* __restrict__ partials,
                              int N, int E) {
    int i = blockIdx.x * BLK + threadIdx.x;
    if (i < N) rowptr[i] = rowptr[i] + partials[i / SCAN_CHUNK];
    if (i == 0) rowptr[N] = (uint32)E;
}

// ---------------- gcursor[b] = rowptr[b*512] ----------------
__global__ void gcur_init_kernel(const uint32* __restrict__ rowptr, uint32* __restrict__ gcursor,
                                 int NB, int N) {
    int b = blockIdx.x * BLK + threadIdx.x;
    if (b < NB) gcursor[b] = rowptr[min(b << NBSHIFT, N)];
}

// ---------------- pass A: bin edges by bucket, LDS-staged, contiguous run writes ----------------
__global__ void binA_kernel(const int* __restrict__ row, const int* __restrict__ col,
                            const float* __restrict__ attr, const float* __restrict__ dinv,
                            uint32* __restrict__ gcursor, int2* __restrict__ binned, int E) {
    __shared__ uint32 hist[256], baseg[256], lstart[256], lcur[256];
    __shared__ int2 stage[TA];
    __shared__ unsigned char sbkt[TA];
    int tid = threadIdx.x;
    int tile = blockIdx.x * TA;
    hist[tid] = 0;
    __syncthreads();

    uint32 px[16], py[16], bk[16];
    #pragma unroll
    for (int k = 0; k < 16; ++k) {
        int e = tile + k * 256 + tid;
        bk[k] = 0xFFFFFFFFu;
        if (e < E) {
            int r = row[e], c = col[e];
            float l = -dinv[r] * attr[e] * dinv[c];
            uint32 b = (uint32)r >> NBSHIFT;
            bk[k] = b;
            px[k] = ((uint32)(r & (NODES_PER_BKT - 1)) << 17) | (uint32)c;
            py[k] = __float_as_uint(l);
            atomicAdd(&hist[b], 1u);
        }
    }
    __syncthreads();
    // exclusive scan of hist (Hillis-Steele inclusive in lcur)
    lcur[tid] = hist[tid];
    __syncthreads();
    for (int off = 1; off < 256; off <<= 1) {
        uint32 t = (tid >= off) ? lcur[tid - off] : 0u;
        __syncthreads();
        lcur[tid] += t;
        __syncthreads();
    }
    lstart[tid] = lcur[tid] - hist[tid];
    if (hist[tid] > 0) baseg[tid] = atomicAdd(&gcursor[tid], hist[tid]);
    lcur[tid] = lstart[tid];
    __syncthreads();
    // stage records grouped by bucket in LDS
    #pragma unroll
    for (int k = 0; k < 16; ++k) {
        if (bk[k] != 0xFFFFFFFFu) {
            uint32 pos = atomicAdd(&lcur[bk[k]], 1u);
            stage[pos] = make_int2((int)px[k], (int)py[k]);
            sbkt[pos] = (unsigned char)bk[k];
        }
    }
    __syncthreads();
    // write runs out: consecutive i -> consecutive dst within each bucket run
    int cnt = min(TA, E - tile);
    for (int i = tid; i < cnt; i += 256) {
        uint32 b = sbkt[i];
        uint32 dst = baseg[b] + (uint32)i - lstart[b];
        binned[dst] = stage[i];
    }
}

// ---------------- pass B: sort within bucket via per-node LDS cursors ----------------
__global__ void binB_kernel(const uint32* __restrict__ rowptr, const int2* __restrict__ binned,
                            int2* __restrict__ pairs, int N) {
    __shared__ uint32 lcur[NODES_PER_BKT];
    int b = blockIdx.x;
    int nodebase = b << NBSHIFT;
    uint32 start = rowptr[nodebase];
    int nodeend = min(nodebase + NODES_PER_BKT, N);
    uint32 end = rowptr[nodeend];
    for (int t = threadIdx.x; t < NODES_PER_BKT; t += 256) {
        int node = nodebase + t;
        lcur[t] = (node < N) ? (rowptr[node] - start) : 0u;
    }
    __syncthreads();
    uint32 cnt = end - start;
    for (uint32 i = threadIdx.x; i < cnt; i += 256) {
        int2 rec = binned[start + i];
        uint32 x = (uint32)rec.x;
        uint32 rl = x >> 17;
        uint32 pos = atomicAdd(&lcur[rl], 1u);
        pairs[start + pos] = make_int2((int)(x & 0x1FFFFu), rec.y);
    }
}

// ---------------- CSR SpMM: out[n,:] = scale * sum_j lap[j]*h[col[j],:]  (- prev[n,:]) ----------------
__global__ void spmm_csr_kernel(const uint32* __restrict__ rowptr, const int2* __restrict__ pairs,
                                const float* __restrict__ h, const float* __restrict__ prev,
                                float* __restrict__ out, float scale, int N) {
    int n = blockIdx.x * (BLK / 64) + (threadIdx.x >> 6);
    if (n >= N) return;
    int lane = threadIdx.x & 63;
    uint32 j = rowptr[n];
    uint32 end = rowptr[n + 1];
    float acc = 0.0f;
    for (; j + 8 <= end; j += 8) {
        int2 p0 = pairs[j + 0], p1 = pairs[j + 1], p2 = pairs[j + 2], p3 = pairs[j + 3];
        int2 p4 = pairs[j + 4], p5 = pairs[j + 5], p6 = pairs[j + 6], p7 = pairs[j + 7];
        float v0 = h[(size_t)p0.x * D + lane];
        float v1 = h[(size_t)p1.x * D + lane];
        float v2 = h[(size_t)p2.x * D + lane];
        float v3 = h[(size_t)p3.x * D + lane];
        float v4 = h[(size_t)p4.x * D + lane];
        float v5 = h[(size_t)p5.x * D + lane];
        float v6 = h[(size_t)p6.x * D + lane];
        float v7 = h[(size_t)p7.x * D + lane];
        acc += __int_as_float(p0.y) * v0 + __int_as_float(p1.y) * v1
             + __int_as_float(p2.y) * v2 + __int_as_float(p3.y) * v3
             + __int_as_float(p4.y) * v4 + __int_as_float(p5.y) * v5
             + __int_as_float(p6.y) * v6 + __int_as_float(p7.y) * v7;
    }
    for (; j < end; ++j) {
        int2 p = pairs[j];
        acc += __int_as_float(p.y) * h[(size_t)p.x * D + lane];
    }
    float r = scale * acc;
    if (prev) r -= prev[(size_t)n * D + lane];
    out[(size_t)n * D + lane] = r;
}

// ---------------- gemm: out[n,:] = (bias or out) + sum_k h_k[n,:] @ W_k ----------------
__global__ void gemm_acc_kernel(const float* __restrict__ h0, const float* __restrict__ h1,
                                const float* __restrict__ W, const float* __restrict__ bias,
                                float* __restrict__ out, int N, int nk, int accumulate) {
    __shared__ float Ws[2 * D * D];
    int tid = threadIdx.x;
    int nload = nk * D * D;
    for (int i = tid * 4; i < nload; i += BLK * 4)
        *(float4*)&Ws[i] = *(const float4*)&W[i];
    __syncthreads();

    int n = blockIdx.x * 16 + (tid >> 4);
    if (n >= N) return;
    int c = (tid & 15) * 4;

    float4 acc;
    if (accumulate) {
        acc = *(float4*)&out[(size_t)n * D + c];
    } else {
        acc = make_float4(bias[c], bias[c + 1], bias[c + 2], bias[c + 3]);
    }

    const float* hs[2] = { h0, h1 };
    for (int k = 0; k < nk; ++k) {
        const float* h = hs[k] + (size_t)n * D;
        const float* Wk = &Ws[k * D * D];
        #pragma unroll
        for (int i4 = 0; i4 < 16; ++i4) {
            float4 hv = *(const float4*)&h[i4 * 4];
            #pragma unroll
            for (int u = 0; u < 4; ++u) {
                float hsv = (u == 0) ? hv.x : (u == 1) ? hv.y : (u == 2) ? hv.z : hv.w;
                float4 wv = *(const float4*)&Wk[(i4 * 4 + u) * D + c];
                acc.x += hsv * wv.x;
                acc.y += hsv * wv.y;
                acc.z += hsv * wv.z;
                acc.w += hsv * wv.w;
            }
        }
    }
    *(float4*)&out[(size_t)n * D + c] = acc;
}

extern "C" void kernel_launch(void* const* d_in, const int* in_sizes, int n_in,
                              void* d_out, int out_size, void* d_ws, size_t ws_size,
                              hipStream_t stream) {
    const float* x    = (const float*)d_in[0];
    const int*   ei   = (const int*)d_in[1];
    const float* attr = (const float*)d_in[2];
    const float* W    = (const float*)d_in[3];   // [4,64,64]
    const float* bias = (const float*)d_in[4];   // [64]
    float* out = (float*)d_out;

    const int N = in_sizes[0] / D;
    const int E = in_sizes[1] / 2;
    const int* row = ei;        // edge_index[0]
    const int* col = ei + E;    // edge_index[1]
    const int NB = (N + NODES_PER_BKT - 1) >> NBSHIFT;

    // workspace layout — 8B-aligned arrays first
    char* p = (char*)d_ws;
    int2*   pairs   = (int2*)p;                  p += (size_t)E * 8;
    float*  T1      = (float*)p;                 p += (size_t)N * D * 4;
    float*  T2      = (float*)p;                 p += (size_t)N * D * 4;
    uint32* deg     = (uint32*)p;                p += (size_t)N * 4;
    uint32* rowptr  = (uint32*)p;                p += (size_t)(N + 1) * 4;
    uint32* gcursor = (uint32*)p;                p += 256 * 4;
    uint32* partials= (uint32*)p;                p += 256 * 4;
    float*  dinv    = (float*)p;                 /* p += N*4 */
    // binned aliases T1: consumed by binB before first spmm writes T1
    int2*   binned  = (int2*)T1;

    const int gE  = (E + BLK - 1) / BLK;
    const int gN  = (N + BLK - 1) / BLK;
    const int nScanBlk = (N + SCAN_CHUNK - 1) / SCAN_CHUNK;
    const int gSp = (N + (BLK / 64) - 1) / (BLK / 64);
    const int gGe = (N + 15) / 16;
    const int gBinA = (E + TA - 1) / TA;

    // ---- build CSR (two-level binned counting sort) + dinv ----
    hipMemsetAsync(deg, 0, (size_t)N * 4, stream);
    deg_kernel<<<gE, BLK, 0, stream>>>(row, deg, E);
    dinv_kernel<<<gN, BLK, 0, stream>>>(deg, dinv, N);
    scan_a_kernel<<<nScanBlk, SCAN_T, 0, stream>>>(deg, rowptr, partials, N);
    scan_b_kernel<<<1, 256, 0, stream>>>(partials, nScanBlk);
    scan_c_kernel<<<gN, BLK, 0, stream>>>(rowptr, partials, N, E);
    gcur_init_kernel<<<1, BLK, 0, stream>>>(rowptr, gcursor, NB, N);
    binA_kernel<<<gBinA, 256, 0, stream>>>(row, col, attr, dinv, gcursor, binned, E);
    binB_kernel<<<NB, 256, 0, stream>>>(rowptr, binned, pairs, N);

    // ---- Chebyshev recurrence ----
    spmm_csr_kernel<<<gSp, BLK, 0, stream>>>(rowptr, pairs, x, nullptr, T1, 1.0f, N);
    gemm_acc_kernel<<<gGe, BLK, 0, stream>>>(x, T1, W, bias, out, N, 2, 0);
    spmm_csr_kernel<<<gSp, BLK, 0, stream>>>(rowptr, pairs, T1, x, T2, 2.0f, N);
    spmm_csr_kernel<<<gSp, BLK, 0, stream>>>(rowptr, pairs, T2, T1, T1, 2.0f, N);
    gemm_acc_kernel<<<gGe, BLK, 0, stream>>>(T2, T1, W + 2 * D * D, nullptr, out, N, 2, 1);
}

// Round 5
// 531.096 us; speedup vs baseline: 8.1961x; 1.0357x over previous
//
#include <hip/hip_runtime.h>

#define D 64
#define BLK 256
#define SCAN_T 256
#define SCAN_E 8
#define SCAN_CHUNK (SCAN_T * SCAN_E)   // 2048 per block

#define NBSHIFT 9
#define NODES_PER_BKT 512              // bucket = row >> 9; NB <= 256 for N <= 131072
#define TA 4096                        // edges per binA tile

typedef unsigned int uint32;
typedef unsigned short ushort16;

// ---- bf16 helpers (RTNE) ----
__device__ inline ushort16 f2bf(float f) {
    uint32 u = __float_as_uint(f);
    u += 0x7FFFu + ((u >> 16) & 1u);
    return (ushort16)(u >> 16);
}
__device__ inline float bf2f(ushort16 s) {
    return __uint_as_float((uint32)s << 16);
}

// ---------------- histogram: deg[row[e]] += 1 ----------------
__global__ void deg_kernel(const int* __restrict__ row, uint32* __restrict__ deg, int E) {
    int e = blockIdx.x * BLK + threadIdx.x;
    if (e < E) atomicAdd(&deg[row[e]], 1u);
}

// ---------------- dinv[n] = deg>0 ? deg^-0.5 : 0 ----------------
__global__ void dinv_kernel(const uint32* __restrict__ deg, float* __restrict__ dinv, int N) {
    int n = blockIdx.x * BLK + threadIdx.x;
    if (n < N) {
        uint32 d = deg[n];
        dinv[n] = (d > 0u) ? rsqrtf((float)d) : 0.0f;
    }
}

// ---------------- x (fp32) -> xb (bf16), vectorized ----------------
__global__ void cvt_kernel(const float* __restrict__ x, ushort16* __restrict__ xb, int n4) {
    int i = blockIdx.x * BLK + threadIdx.x;
    if (i < n4) {
        float4 v = ((const float4*)x)[i];
        ushort16 o0 = f2bf(v.x), o1 = f2bf(v.y), o2 = f2bf(v.z), o3 = f2bf(v.w);
        uint2 pack;
        pack.x = (uint32)o0 | ((uint32)o1 << 16);
        pack.y = (uint32)o2 | ((uint32)o3 << 16);
        ((uint2*)xb)[i] = pack;
    }
}

// ---------------- scan A ----------------
__global__ void scan_a_kernel(const uint32* __restrict__ deg, uint32* __restrict__ rowptr,
                              uint32* __restrict__ partials, int N) {
    __shared__ uint32 sums[SCAN_T];
    int tid = threadIdx.x;
    int base = blockIdx.x * SCAN_CHUNK + tid * SCAN_E;
    uint32 v[SCAN_E];
    uint32 s = 0;
    #pragma unroll
    for (int i = 0; i < SCAN_E; ++i) {
        uint32 d = (base + i < N) ? deg[base + i] : 0u;
        v[i] = s;
        s += d;
    }
    sums[tid] = s;
    __syncthreads();
    for (int off = 1; off < SCAN_T; off <<= 1) {
        uint32 t = (tid >= off) ? sums[tid - off] : 0u;
        __syncthreads();
        sums[tid] += t;
        __syncthreads();
    }
    uint32 excl = (tid > 0) ? sums[tid - 1] : 0u;
    #pragma unroll
    for (int i = 0; i < SCAN_E; ++i) {
        if (base + i < N) rowptr[base + i] = excl + v[i];
    }
    if (tid == SCAN_T - 1) partials[blockIdx.x] = sums[SCAN_T - 1];
}

__global__ void scan_b_kernel(uint32* __restrict__ partials, int nblk) {
    __shared__ uint32 buf[256];
    int tid = threadIdx.x;
    if (tid < nblk) buf[tid] = partials[tid];
    __syncthreads();
    if (tid == 0) {
        uint32 run = 0;
        for (int i = 0; i < nblk; ++i) { uint32 t = buf[i]; buf[i] = run; run += t; }
    }
    __syncthreads();
    if (tid < nblk) partials[tid] = buf[tid];
}

__global__ void scan_c_kernel(uint32* __restrict__ rowptr, const uint32* __restrict__ partials,
                              int N, int E) {
    int i = blockIdx.x * BLK + threadIdx.x;
    if (i < N) rowptr[i] = rowptr[i] + partials[i / SCAN_CHUNK];
    if (i == 0) rowptr[N] = (uint32)E;
}

__global__ void gcur_init_kernel(const uint32* __restrict__ rowptr, uint32* __restrict__ gcursor,
                                 int NB, int N) {
    int b = blockIdx.x * BLK + threadIdx.x;
    if (b < NB) gcursor[b] = rowptr[min(b << NBSHIFT, N)];
}

// ---------------- pass A: bin edges by bucket, LDS-staged, contiguous run writes ----------------
__global__ void binA_kernel(const int* __restrict__ row, const int* __restrict__ col,
                            const float* __restrict__ attr, const float* __restrict__ dinv,
                            uint32* __restrict__ gcursor, int2* __restrict__ binned, int E) {
    __shared__ uint32 hist[256], baseg[256], lstart[256], lcur[256];
    __shared__ int2 stage[TA];
    __shared__ unsigned char sbkt[TA];
    int tid = threadIdx.x;
    int tile = blockIdx.x * TA;
    hist[tid] = 0;
    __syncthreads();

    uint32 px[16], py[16], bk[16];
    #pragma unroll
    for (int k = 0; k < 16; ++k) {
        int e = tile + k * 256 + tid;
        bk[k] = 0xFFFFFFFFu;
        if (e < E) {
            int r = row[e], c = col[e];
            float l = -dinv[r] * attr[e] * dinv[c];
            uint32 b = (uint32)r >> NBSHIFT;
            bk[k] = b;
            px[k] = ((uint32)(r & (NODES_PER_BKT - 1)) << 17) | (uint32)c;
            py[k] = __float_as_uint(l);
            atomicAdd(&hist[b], 1u);
        }
    }
    __syncthreads();
    lcur[tid] = hist[tid];
    __syncthreads();
    for (int off = 1; off < 256; off <<= 1) {
        uint32 t = (tid >= off) ? lcur[tid - off] : 0u;
        __syncthreads();
        lcur[tid] += t;
        __syncthreads();
    }
    lstart[tid] = lcur[tid] - hist[tid];
    if (hist[tid] > 0) baseg[tid] = atomicAdd(&gcursor[tid], hist[tid]);
    lcur[tid] = lstart[tid];
    __syncthreads();
    #pragma unroll
    for (int k = 0; k < 16; ++k) {
        if (bk[k] != 0xFFFFFFFFu) {
            uint32 pos = atomicAdd(&lcur[bk[k]], 1u);
            stage[pos] = make_int2((int)px[k], (int)py[k]);
            sbkt[pos] = (unsigned char)bk[k];
        }
    }
    __syncthreads();
    int cnt = min(TA, E - tile);
    for (int i = tid; i < cnt; i += 256) {
        uint32 b = sbkt[i];
        uint32 dst = baseg[b] + (uint32)i - lstart[b];
        binned[dst] = stage[i];
    }
}

// ---------------- pass B: sort within bucket via per-node LDS cursors ----------------
__global__ void binB_kernel(const uint32* __restrict__ rowptr, const int2* __restrict__ binned,
                            int2* __restrict__ pairs, int N) {
    __shared__ uint32 lcur[NODES_PER_BKT];
    int b = blockIdx.x;
    int nodebase = b << NBSHIFT;
    uint32 start = rowptr[nodebase];
    int nodeend = min(nodebase + NODES_PER_BKT, N);
    uint32 end = rowptr[nodeend];
    for (int t = threadIdx.x; t < NODES_PER_BKT; t += 256) {
        int node = nodebase + t;
        lcur[t] = (node < N) ? (rowptr[node] - start) : 0u;
    }
    __syncthreads();
    uint32 cnt = end - start;
    for (uint32 i = threadIdx.x; i < cnt; i += 256) {
        int2 rec = binned[start + i];
        uint32 x = (uint32)rec.x;
        uint32 rl = x >> 17;
        uint32 pos = atomicAdd(&lcur[rl], 1u);
        pairs[start + pos] = make_int2((int)(x & 0x1FFFFu), rec.y);
    }
}

// ---------------- CSR SpMM (bf16 storage, fp32 accumulate) ----------------
// out[n,:] = bf16( scale * sum_j lap[j]*h[col[j],:]  - prev[n,:] )
__global__ void spmm_csr_bf16(const uint32* __restrict__ rowptr, const int2* __restrict__ pairs,
                              const ushort16* __restrict__ h, const ushort16* __restrict__ prev,
                              ushort16* __restrict__ out, float scale, int N) {
    int n = blockIdx.x * (BLK / 64) + (threadIdx.x >> 6);
    if (n >= N) return;
    int lane = threadIdx.x & 63;
    uint32 j = rowptr[n];
    uint32 end = rowptr[n + 1];
    float acc = 0.0f;
    for (; j + 8 <= end; j += 8) {
        int2 p0 = pairs[j + 0], p1 = pairs[j + 1], p2 = pairs[j + 2], p3 = pairs[j + 3];
        int2 p4 = pairs[j + 4], p5 = pairs[j + 5], p6 = pairs[j + 6], p7 = pairs[j + 7];
        float v0 = bf2f(h[(size_t)p0.x * D + lane]);
        float v1 = bf2f(h[(size_t)p1.x * D + lane]);
        float v2 = bf2f(h[(size_t)p2.x * D + lane]);
        float v3 = bf2f(h[(size_t)p3.x * D + lane]);
        float v4 = bf2f(h[(size_t)p4.x * D + lane]);
        float v5 = bf2f(h[(size_t)p5.x * D + lane]);
        float v6 = bf2f(h[(size_t)p6.x * D + lane]);
        float v7 = bf2f(h[(size_t)p7.x * D + lane]);
        acc += __int_as_float(p0.y) * v0 + __int_as_float(p1.y) * v1
             + __int_as_float(p2.y) * v2 + __int_as_float(p3.y) * v3
             + __int_as_float(p4.y) * v4 + __int_as_float(p5.y) * v5
             + __int_as_float(p6.y) * v6 + __int_as_float(p7.y) * v7;
    }
    for (; j < end; ++j) {
        int2 p = pairs[j];
        acc += __int_as_float(p.y) * bf2f(h[(size_t)p.x * D + lane]);
    }
    float r = scale * acc;
    if (prev) r -= bf2f(prev[(size_t)n * D + lane]);
    out[(size_t)n * D + lane] = f2bf(r);
}

// ---------------- gemm: out[n,:] = (bias or out) + sum_k bf16 h_k[n,:] @ W_k ----------------
__global__ void gemm_acc_bf16(const ushort16* __restrict__ h0, const ushort16* __restrict__ h1,
                              const float* __restrict__ W, const float* __restrict__ bias,
                              float* __restrict__ out, int N, int nk, int accumulate) {
    __shared__ float Ws[2 * D * D];
    int tid = threadIdx.x;
    int nload = nk * D * D;
    for (int i = tid * 4; i < nload; i += BLK * 4)
        *(float4*)&Ws[i] = *(const float4*)&W[i];
    __syncthreads();

    int n = blockIdx.x * 16 + (tid >> 4);
    if (n >= N) return;
    int c = (tid & 15) * 4;

    float4 acc;
    if (accumulate) {
        acc = *(float4*)&out[(size_t)n * D + c];
    } else {
        acc = make_float4(bias[c], bias[c + 1], bias[c + 2], bias[c + 3]);
    }

    const ushort16* hs[2] = { h0, h1 };
    for (int k = 0; k < nk; ++k) {
        const ushort16* h = hs[k] + (size_t)n * D;
        const float* Wk = &Ws[k * D * D];
        #pragma unroll
        for (int i4 = 0; i4 < 16; ++i4) {
            uint2 u = *(const uint2*)&h[i4 * 4];
            float f0 = __uint_as_float(u.x << 16);
            float f1 = __uint_as_float(u.x & 0xFFFF0000u);
            float f2 = __uint_as_float(u.y << 16);
            float f3 = __uint_as_float(u.y & 0xFFFF0000u);
            float fv[4] = { f0, f1, f2, f3 };
            #pragma unroll
            for (int u2 = 0; u2 < 4; ++u2) {
                float4 wv = *(const float4*)&Wk[(i4 * 4 + u2) * D + c];
                acc.x += fv[u2] * wv.x;
                acc.y += fv[u2] * wv.y;
                acc.z += fv[u2] * wv.z;
                acc.w += fv[u2] * wv.w;
            }
        }
    }
    *(float4*)&out[(size_t)n * D + c] = acc;
}

extern "C" void kernel_launch(void* const* d_in, const int* in_sizes, int n_in,
                              void* d_out, int out_size, void* d_ws, size_t ws_size,
                              hipStream_t stream) {
    const float* x    = (const float*)d_in[0];
    const int*   ei   = (const int*)d_in[1];
    const float* attr = (const float*)d_in[2];
    const float* W    = (const float*)d_in[3];   // [4,64,64]
    const float* bias = (const float*)d_in[4];   // [64]
    float* out = (float*)d_out;

    const int N = in_sizes[0] / D;
    const int E = in_sizes[1] / 2;
    const int* row = ei;        // edge_index[0]
    const int* col = ei + E;    // edge_index[1]
    const int NB = (N + NODES_PER_BKT - 1) >> NBSHIFT;

    // workspace layout — 8B-aligned arrays first
    char* p = (char*)d_ws;
    int2*     pairs   = (int2*)p;                p += (size_t)E * 8;
    ushort16* xb      = (ushort16*)p;            p += (size_t)N * D * 2;
    ushort16* T1      = (ushort16*)p;            p += (size_t)N * D * 2;
    ushort16* T2      = (ushort16*)p;            p += (size_t)N * D * 2;
    uint32*   deg     = (uint32*)p;              p += (size_t)N * 4;
    uint32*   rowptr  = (uint32*)p;              p += (size_t)(N + 1) * 4;
    uint32*   gcursor = (uint32*)p;              p += 256 * 4;
    uint32*   partials= (uint32*)p;              p += 256 * 4;
    float*    dinv    = (float*)p;               /* p += N*4 */
    // binned aliases T2 (N*D*2 == E*8 here): consumed by binB before spmm writes T2
    int2*     binned  = (int2*)T2;

    const int gE  = (E + BLK - 1) / BLK;
    const int gN  = (N + BLK - 1) / BLK;
    const int nScanBlk = (N + SCAN_CHUNK - 1) / SCAN_CHUNK;
    const int gSp = (N + (BLK / 64) - 1) / (BLK / 64);
    const int gGe = (N + 15) / 16;
    const int gBinA = (E + TA - 1) / TA;
    const int gCvt = ((N * D / 4) + BLK - 1) / BLK;

    // ---- build CSR (two-level binned counting sort) + dinv + bf16 x ----
    hipMemsetAsync(deg, 0, (size_t)N * 4, stream);
    deg_kernel<<<gE, BLK, 0, stream>>>(row, deg, E);
    dinv_kernel<<<gN, BLK, 0, stream>>>(deg, dinv, N);
    cvt_kernel<<<gCvt, BLK, 0, stream>>>(x, xb, N * D / 4);
    scan_a_kernel<<<nScanBlk, SCAN_T, 0, stream>>>(deg, rowptr, partials, N);
    scan_b_kernel<<<1, 256, 0, stream>>>(partials, nScanBlk);
    scan_c_kernel<<<gN, BLK, 0, stream>>>(rowptr, partials, N, E);
    gcur_init_kernel<<<1, BLK, 0, stream>>>(rowptr, gcursor, NB, N);
    binA_kernel<<<gBinA, 256, 0, stream>>>(row, col, attr, dinv, gcursor, binned, E);
    binB_kernel<<<NB, 256, 0, stream>>>(rowptr, binned, pairs, N);

    // ---- Chebyshev recurrence (bf16 storage, fp32 math) ----
    // T1 = spmm(xb)
    spmm_csr_bf16<<<gSp, BLK, 0, stream>>>(rowptr, pairs, xb, nullptr, T1, 1.0f, N);
    // out = bias + x@W0 + T1@W1
    gemm_acc_bf16<<<gGe, BLK, 0, stream>>>(xb, T1, W, bias, out, N, 2, 0);
    // T2 = 2*spmm(T1) - x     (overwrites binned — already consumed)
    spmm_csr_bf16<<<gSp, BLK, 0, stream>>>(rowptr, pairs, T1, xb, T2, 2.0f, N);
    // T1' = 2*spmm(T2) - T1   (in place: reads prev[n,lane], writes same slot)
    spmm_csr_bf16<<<gSp, BLK, 0, stream>>>(rowptr, pairs, T2, T1, T1, 2.0f, N);
    // out += T2@W2 + T1'@W3
    gemm_acc_bf16<<<gGe, BLK, 0, stream>>>(T2, T1, W + 2 * D * D, nullptr, out, N, 2, 1);
}

// Round 6
// 431.265 us; speedup vs baseline: 10.0934x; 1.2315x over previous
//
#include <hip/hip_runtime.h>

#define D 64
#define BLK 256
#define SCAN_T 256
#define SCAN_E 8
#define SCAN_CHUNK (SCAN_T * SCAN_E)   // 2048 per block

#define NBSHIFT 9
#define NODES_PER_BKT 512              // bucket = row >> 9; NB <= 256 for N <= 131072
#define TA 4096                        // edges per binA tile

typedef unsigned int uint32;
typedef unsigned short ushort16;

// ---- bf16 helpers (RTNE) ----
__device__ inline uint32 f2bf_u(float f) {
    uint32 u = __float_as_uint(f);
    u += 0x7FFFu + ((u >> 16) & 1u);
    return u >> 16;
}
__device__ inline float bf2f(ushort16 s) {
    return __uint_as_float((uint32)s << 16);
}

// ---------------- histogram: deg[row[e]] += 1 ----------------
__global__ void deg_kernel(const int* __restrict__ row, uint32* __restrict__ deg, int E) {
    int e = blockIdx.x * BLK + threadIdx.x;
    if (e < E) atomicAdd(&deg[row[e]], 1u);
}

// ---------------- x (fp32) -> xb (bf16), vectorized ----------------
__global__ void cvt_kernel(const float* __restrict__ x, uint2* __restrict__ xb, int n4) {
    int i = blockIdx.x * BLK + threadIdx.x;
    if (i < n4) {
        float4 v = ((const float4*)x)[i];
        uint2 pack;
        pack.x = f2bf_u(v.x) | (f2bf_u(v.y) << 16);
        pack.y = f2bf_u(v.z) | (f2bf_u(v.w) << 16);
        xb[i] = pack;
    }
}

// ---------------- scan A (+ fused dinv) ----------------
__global__ void scan_a_kernel(const uint32* __restrict__ deg, uint32* __restrict__ rowptr,
                              uint32* __restrict__ partials, float* __restrict__ dinv, int N) {
    __shared__ uint32 sums[SCAN_T];
    int tid = threadIdx.x;
    int base = blockIdx.x * SCAN_CHUNK + tid * SCAN_E;
    uint32 v[SCAN_E];
    uint32 s = 0;
    #pragma unroll
    for (int i = 0; i < SCAN_E; ++i) {
        uint32 d = (base + i < N) ? deg[base + i] : 0u;
        if (base + i < N) dinv[base + i] = (d > 0u) ? rsqrtf((float)d) : 0.0f;
        v[i] = s;
        s += d;
    }
    sums[tid] = s;
    __syncthreads();
    for (int off = 1; off < SCAN_T; off <<= 1) {
        uint32 t = (tid >= off) ? sums[tid - off] : 0u;
        __syncthreads();
        sums[tid] += t;
        __syncthreads();
    }
    uint32 excl = (tid > 0) ? sums[tid - 1] : 0u;
    #pragma unroll
    for (int i = 0; i < SCAN_E; ++i) {
        if (base + i < N) rowptr[base + i] = excl + v[i];
    }
    if (tid == SCAN_T - 1) partials[blockIdx.x] = sums[SCAN_T - 1];
}

__global__ void scan_b_kernel(uint32* __restrict__ partials, int nblk) {
    __shared__ uint32 buf[256];
    int tid = threadIdx.x;
    if (tid < nblk) buf[tid] = partials[tid];
    __syncthreads();
    if (tid == 0) {
        uint32 run = 0;
        for (int i = 0; i < nblk; ++i) { uint32 t = buf[i]; buf[i] = run; run += t; }
    }
    __syncthreads();
    if (tid < nblk) partials[tid] = buf[tid];
}

// ---------------- scan C (+ fused gcursor init) ----------------
__global__ void scan_c_kernel(uint32* __restrict__ rowptr, const uint32* __restrict__ partials,
                              uint32* __restrict__ gcursor, int N, int E) {
    int i = blockIdx.x * BLK + threadIdx.x;
    if (i < N) {
        uint32 r = rowptr[i] + partials[i / SCAN_CHUNK];
        rowptr[i] = r;
        if ((i & (NODES_PER_BKT - 1)) == 0) gcursor[i >> NBSHIFT] = r;
    }
    if (i == 0) rowptr[N] = (uint32)E;
}

// ---------------- pass A: bin edges by bucket, LDS-staged, contiguous run writes ----------------
__global__ void binA_kernel(const int* __restrict__ row, const int* __restrict__ col,
                            const float* __restrict__ attr, const float* __restrict__ dinv,
                            uint32* __restrict__ gcursor, int2* __restrict__ binned, int E) {
    __shared__ uint32 hist[256], baseg[256], lstart[256], lcur[256];
    __shared__ int2 stage[TA];
    __shared__ unsigned char sbkt[TA];
    int tid = threadIdx.x;
    int tile = blockIdx.x * TA;
    hist[tid] = 0;
    __syncthreads();

    uint32 px[16], py[16], bk[16];
    #pragma unroll
    for (int k = 0; k < 16; ++k) {
        int e = tile + k * 256 + tid;
        bk[k] = 0xFFFFFFFFu;
        if (e < E) {
            int r = row[e], c = col[e];
            float l = -dinv[r] * attr[e] * dinv[c];
            uint32 b = (uint32)r >> NBSHIFT;
            bk[k] = b;
            px[k] = ((uint32)(r & (NODES_PER_BKT - 1)) << 17) | (uint32)c;
            py[k] = __float_as_uint(l);
            atomicAdd(&hist[b], 1u);
        }
    }
    __syncthreads();
    lcur[tid] = hist[tid];
    __syncthreads();
    for (int off = 1; off < 256; off <<= 1) {
        uint32 t = (tid >= off) ? lcur[tid - off] : 0u;
        __syncthreads();
        lcur[tid] += t;
        __syncthreads();
    }
    lstart[tid] = lcur[tid] - hist[tid];
    if (hist[tid] > 0) baseg[tid] = atomicAdd(&gcursor[tid], hist[tid]);
    lcur[tid] = lstart[tid];
    __syncthreads();
    #pragma unroll
    for (int k = 0; k < 16; ++k) {
        if (bk[k] != 0xFFFFFFFFu) {
            uint32 pos = atomicAdd(&lcur[bk[k]], 1u);
            stage[pos] = make_int2((int)px[k], (int)py[k]);
            sbkt[pos] = (unsigned char)bk[k];
        }
    }
    __syncthreads();
    int cnt = min(TA, E - tile);
    for (int i = tid; i < cnt; i += 256) {
        uint32 b = sbkt[i];
        uint32 dst = baseg[b] + (uint32)i - lstart[b];
        binned[dst] = stage[i];
    }
}

// ---------------- pass B: sort within bucket; pairs.x = col<<7 (byte offset of bf16 row) ----------------
__global__ void binB_kernel(const uint32* __restrict__ rowptr, const int2* __restrict__ binned,
                            int2* __restrict__ pairs, int N) {
    __shared__ uint32 lcur[NODES_PER_BKT];
    int b = blockIdx.x;
    int nodebase = b << NBSHIFT;
    uint32 start = rowptr[nodebase];
    int nodeend = min(nodebase + NODES_PER_BKT, N);
    uint32 end = rowptr[nodeend];
    for (int t = threadIdx.x; t < NODES_PER_BKT; t += 256) {
        int node = nodebase + t;
        lcur[t] = (node < N) ? (rowptr[node] - start) : 0u;
    }
    __syncthreads();
    uint32 cnt = end - start;
    for (uint32 i = threadIdx.x; i < cnt; i += 256) {
        int2 rec = binned[start + i];
        uint32 x = (uint32)rec.x;
        uint32 rl = x >> 17;
        uint32 pos = atomicAdd(&lcur[rl], 1u);
        pairs[start + pos] = make_int2((int)((x & 0x1FFFFu) << 7), rec.y);
    }
}

// ---------------- CSR SpMM v4: 16 lanes/edge, uint2 gathers, 4 edges per wave-instruction ----------------
// out[n,:] = bf16( scale * sum_j lap[j]*h[col[j],:] - prev[n,:] ); one wave per node.
__global__ void spmm4_kernel(const uint32* __restrict__ rowptr, const int2* __restrict__ pairs,
                             const char* __restrict__ hb, const uint2* __restrict__ prev,
                             uint2* __restrict__ out, float scale, int N) {
    int n = blockIdx.x * 4 + (threadIdx.x >> 6);
    if (n >= N) return;
    int lane = threadIdx.x & 63;
    int q = lane >> 4;          // quarter: which of the 4 concurrent edges
    int sub = lane & 15;        // 4 columns per lane: [sub*4, sub*4+4)
    int off = sub * 8;          // byte offset within a 128B row
    uint32 j = rowptr[n];
    uint32 end = rowptr[n + 1];
    float a0 = 0.f, a1 = 0.f, a2 = 0.f, a3 = 0.f;

    // main: 8 edges per iter (two quartets), 4 loads in flight
    for (; j + 8 <= end; j += 8) {
        int2 m0 = pairs[j + q];
        int2 m1 = pairs[j + 4 + q];
        uint2 h0 = *(const uint2*)(hb + (uint32)m0.x + off);
        uint2 h1 = *(const uint2*)(hb + (uint32)m1.x + off);
        float l0 = __int_as_float(m0.y);
        float l1 = __int_as_float(m1.y);
        a0 += l0 * __uint_as_float(h0.x << 16);
        a1 += l0 * __uint_as_float(h0.x & 0xFFFF0000u);
        a2 += l0 * __uint_as_float(h0.y << 16);
        a3 += l0 * __uint_as_float(h0.y & 0xFFFF0000u);
        a0 += l1 * __uint_as_float(h1.x << 16);
        a1 += l1 * __uint_as_float(h1.x & 0xFFFF0000u);
        a2 += l1 * __uint_as_float(h1.y << 16);
        a3 += l1 * __uint_as_float(h1.y & 0xFFFF0000u);
    }
    // tail: quartets with masking (safe: loop only entered when end > j, so end-1 >= j)
    for (; j < end; j += 4) {
        uint32 idx = j + q;
        bool act = idx < end;
        uint32 ci = act ? idx : (end - 1);
        int2 m = pairs[ci];
        float l = act ? __int_as_float(m.y) : 0.0f;
        uint2 h0 = *(const uint2*)(hb + (uint32)m.x + off);
        a0 += l * __uint_as_float(h0.x << 16);
        a1 += l * __uint_as_float(h0.x & 0xFFFF0000u);
        a2 += l * __uint_as_float(h0.y << 16);
        a3 += l * __uint_as_float(h0.y & 0xFFFF0000u);
    }
    // reduce across quarters (cols identical for lanes with same sub)
    a0 += __shfl_xor(a0, 16); a0 += __shfl_xor(a0, 32);
    a1 += __shfl_xor(a1, 16); a1 += __shfl_xor(a1, 32);
    a2 += __shfl_xor(a2, 16); a2 += __shfl_xor(a2, 32);
    a3 += __shfl_xor(a3, 16); a3 += __shfl_xor(a3, 32);

    if (q == 0) {
        float r0 = scale * a0, r1 = scale * a1, r2 = scale * a2, r3 = scale * a3;
        size_t slot = (size_t)n * 16 + sub;   // uint2 index: 16 per row
        if (prev) {
            uint2 pv = prev[slot];
            r0 -= __uint_as_float(pv.x << 16);
            r1 -= __uint_as_float(pv.x & 0xFFFF0000u);
            r2 -= __uint_as_float(pv.y << 16);
            r3 -= __uint_as_float(pv.y & 0xFFFF0000u);
        }
        uint2 pack;
        pack.x = f2bf_u(r0) | (f2bf_u(r1) << 16);
        pack.y = f2bf_u(r2) | (f2bf_u(r3) << 16);
        out[slot] = pack;
    }
}

// ---------------- gemm: out[n,:] = (bias or out) + sum_k bf16 h_k[n,:] @ W_k ----------------
__global__ void gemm_acc_bf16(const ushort16* __restrict__ h0, const ushort16* __restrict__ h1,
                              const float* __restrict__ W, const float* __restrict__ bias,
                              float* __restrict__ out, int N, int nk, int accumulate) {
    __shared__ float Ws[2 * D * D];
    int tid = threadIdx.x;
    int nload = nk * D * D;
    for (int i = tid * 4; i < nload; i += BLK * 4)
        *(float4*)&Ws[i] = *(const float4*)&W[i];
    __syncthreads();

    int n = blockIdx.x * 16 + (tid >> 4);
    if (n >= N) return;
    int c = (tid & 15) * 4;

    float4 acc;
    if (accumulate) {
        acc = *(float4*)&out[(size_t)n * D + c];
    } else {
        acc = make_float4(bias[c], bias[c + 1], bias[c + 2], bias[c + 3]);
    }

    const ushort16* hs[2] = { h0, h1 };
    for (int k = 0; k < nk; ++k) {
        const ushort16* h = hs[k] + (size_t)n * D;
        const float* Wk = &Ws[k * D * D];
        #pragma unroll
        for (int i4 = 0; i4 < 16; ++i4) {
            uint2 u = *(const uint2*)&h[i4 * 4];
            float f0 = __uint_as_float(u.x << 16);
            float f1 = __uint_as_float(u.x & 0xFFFF0000u);
            float f2 = __uint_as_float(u.y << 16);
            float f3 = __uint_as_float(u.y & 0xFFFF0000u);
            float fv[4] = { f0, f1, f2, f3 };
            #pragma unroll
            for (int u2 = 0; u2 < 4; ++u2) {
                float4 wv = *(const float4*)&Wk[(i4 * 4 + u2) * D + c];
                acc.x += fv[u2] * wv.x;
                acc.y += fv[u2] * wv.y;
                acc.z += fv[u2] * wv.z;
                acc.w += fv[u2] * wv.w;
            }
        }
    }
    *(float4*)&out[(size_t)n * D + c] = acc;
}

extern "C" void kernel_launch(void* const* d_in, const int* in_sizes, int n_in,
                              void* d_out, int out_size, void* d_ws, size_t ws_size,
                              hipStream_t stream) {
    const float* x    = (const float*)d_in[0];
    const int*   ei   = (const int*)d_in[1];
    const float* attr = (const float*)d_in[2];
    const float* W    = (const float*)d_in[3];   // [4,64,64]
    const float* bias = (const float*)d_in[4];   // [64]
    float* out = (float*)d_out;

    const int N = in_sizes[0] / D;
    const int E = in_sizes[1] / 2;
    const int* row = ei;        // edge_index[0]
    const int* col = ei + E;    // edge_index[1]
    const int NB = (N + NODES_PER_BKT - 1) >> NBSHIFT;

    // workspace layout — 8B-aligned arrays first
    char* p = (char*)d_ws;
    int2*     pairs   = (int2*)p;                p += (size_t)E * 8;
    uint2*    xb      = (uint2*)p;               p += (size_t)N * D * 2;
    uint2*    T1      = (uint2*)p;               p += (size_t)N * D * 2;
    uint2*    T2      = (uint2*)p;               p += (size_t)N * D * 2;
    uint32*   deg     = (uint32*)p;              p += (size_t)N * 4;
    uint32*   rowptr  = (uint32*)p;              p += (size_t)(N + 1) * 4;
    uint32*   gcursor = (uint32*)p;              p += 256 * 4;
    uint32*   partials= (uint32*)p;              p += 256 * 4;
    float*    dinv    = (float*)p;               /* p += N*4 */
    // binned aliases T2 (N*D*2 == E*8 here): consumed by binB before spmm writes T2
    int2*     binned  = (int2*)T2;

    const int gE  = (E + BLK - 1) / BLK;
    const int gN  = (N + BLK - 1) / BLK;
    const int nScanBlk = (N + SCAN_CHUNK - 1) / SCAN_CHUNK;
    const int gSp = (N + 3) / 4;
    const int gGe = (N + 15) / 16;
    const int gBinA = (E + TA - 1) / TA;
    const int gCvt = ((N * D / 4) + BLK - 1) / BLK;

    // ---- build CSR (two-level binned counting sort) + dinv + bf16 x ----
    hipMemsetAsync(deg, 0, (size_t)N * 4, stream);
    deg_kernel<<<gE, BLK, 0, stream>>>(row, deg, E);
    cvt_kernel<<<gCvt, BLK, 0, stream>>>(x, xb, N * D / 4);
    scan_a_kernel<<<nScanBlk, SCAN_T, 0, stream>>>(deg, rowptr, partials, dinv, N);
    scan_b_kernel<<<1, 256, 0, stream>>>(partials, nScanBlk);
    scan_c_kernel<<<gN, BLK, 0, stream>>>(rowptr, partials, gcursor, N, E);
    binA_kernel<<<gBinA, 256, 0, stream>>>(row, col, attr, dinv, gcursor, binned, E);
    binB_kernel<<<NB, 256, 0, stream>>>(rowptr, binned, pairs, N);

    // ---- Chebyshev recurrence (bf16 storage, fp32 math) ----
    // T1 = spmm(xb)
    spmm4_kernel<<<gSp, BLK, 0, stream>>>(rowptr, pairs, (const char*)xb, nullptr, T1, 1.0f, N);
    // out = bias + x@W0 + T1@W1
    gemm_acc_bf16<<<gGe, BLK, 0, stream>>>((const ushort16*)xb, (const ushort16*)T1, W, bias, out, N, 2, 0);
    // T2 = 2*spmm(T1) - x     (overwrites binned — already consumed)
    spmm4_kernel<<<gSp, BLK, 0, stream>>>(rowptr, pairs, (const char*)T1, xb, T2, 2.0f, N);
    // T1' = 2*spmm(T2) - T1   (in place: reads prev[n,lane] before writing same slot)
    spmm4_kernel<<<gSp, BLK, 0, stream>>>(rowptr, pairs, (const char*)T2, T1, T1, 2.0f, N);
    // out += T2@W2 + T1'@W3
    gemm_acc_bf16<<<gGe, BLK, 0, stream>>>((const ushort16*)T2, (const ushort16*)T1, W + 2 * D * D, nullptr, out, N, 2, 1);
}

// Round 7
// 387.599 us; speedup vs baseline: 11.2305x; 1.1127x over previous
//
#include <hip/hip_runtime.h>

#define D 64
#define BLK 256

#define NBSHIFT 9
#define NODES_PER_BKT 512              // bucket = row >> 9; NB <= 256 for N <= 131072
#define TA 4096                        // edges per binA tile

typedef unsigned int uint32;
typedef unsigned short ushort16;

// ---- bf16 helpers (RTNE) ----
__device__ inline uint32 f2bf_u(float f) {
    uint32 u = __float_as_uint(f);
    u += 0x7FFFu + ((u >> 16) & 1u);
    return u >> 16;
}

// ---------------- x (fp32) -> xb (bf16), vectorized ----------------
__global__ void cvt_kernel(const float* __restrict__ x, uint2* __restrict__ xb, int n4) {
    int i = blockIdx.x * BLK + threadIdx.x;
    if (i < n4) {
        float4 v = ((const float4*)x)[i];
        uint2 pack;
        pack.x = f2bf_u(v.x) | (f2bf_u(v.y) << 16);
        pack.y = f2bf_u(v.z) | (f2bf_u(v.w) << 16);
        xb[i] = pack;
    }
}

// ---------------- bucket histogram: LDS-staged, 256 global atomics per block ----------------
__global__ void hist_kernel(const int* __restrict__ row, uint32* __restrict__ bcount, int E) {
    __shared__ uint32 h[256];
    int tid = threadIdx.x;
    h[tid] = 0;
    __syncthreads();
    int base = blockIdx.x * TA;
    int end = min(base + TA, E);
    for (int e = base + tid; e < end; e += 256)
        atomicAdd(&h[(uint32)row[e] >> NBSHIFT], 1u);
    __syncthreads();
    if (h[tid]) atomicAdd(&bcount[tid], h[tid]);
}

// ---------------- scan of 256 bucket counts -> gcursor (mutable) + bbase (stable) ----------------
__global__ void scan256_kernel(const uint32* __restrict__ bcount, uint32* __restrict__ gcursor,
                               uint32* __restrict__ bbase, int E) {
    __shared__ uint32 s[256];
    int tid = threadIdx.x;
    uint32 v = bcount[tid];
    s[tid] = v;
    __syncthreads();
    for (int off = 1; off < 256; off <<= 1) {
        uint32 t = (tid >= off) ? s[tid - off] : 0u;
        __syncthreads();
        s[tid] += t;
        __syncthreads();
    }
    uint32 excl = s[tid] - v;
    gcursor[tid] = excl;
    bbase[tid] = excl;
    if (tid == 255) bbase[256] = (uint32)E;
}

// ---------------- pass A: bin (rowlocal<<17|col, attr) by bucket, LDS-staged run writes ----------------
__global__ void binA_kernel(const int* __restrict__ row, const int* __restrict__ col,
                            const float* __restrict__ attr,
                            uint32* __restrict__ gcursor, int2* __restrict__ binned, int E) {
    __shared__ uint32 hist[256], baseg[256], lstart[256], lcur[256];
    __shared__ int2 stage[TA];
    __shared__ unsigned char sbkt[TA];
    int tid = threadIdx.x;
    int tile = blockIdx.x * TA;
    hist[tid] = 0;
    __syncthreads();

    uint32 px[16], py[16], bk[16];
    #pragma unroll
    for (int k = 0; k < 16; ++k) {
        int e = tile + k * 256 + tid;
        bk[k] = 0xFFFFFFFFu;
        if (e < E) {
            int r = row[e], c = col[e];
            uint32 b = (uint32)r >> NBSHIFT;
            bk[k] = b;
            px[k] = ((uint32)(r & (NODES_PER_BKT - 1)) << 17) | (uint32)c;
            py[k] = __float_as_uint(attr[e]);
            atomicAdd(&hist[b], 1u);
        }
    }
    __syncthreads();
    lcur[tid] = hist[tid];
    __syncthreads();
    for (int off = 1; off < 256; off <<= 1) {
        uint32 t = (tid >= off) ? lcur[tid - off] : 0u;
        __syncthreads();
        lcur[tid] += t;
        __syncthreads();
    }
    lstart[tid] = lcur[tid] - hist[tid];
    if (hist[tid] > 0) baseg[tid] = atomicAdd(&gcursor[tid], hist[tid]);
    lcur[tid] = lstart[tid];
    __syncthreads();
    #pragma unroll
    for (int k = 0; k < 16; ++k) {
        if (bk[k] != 0xFFFFFFFFu) {
            uint32 pos = atomicAdd(&lcur[bk[k]], 1u);
            stage[pos] = make_int2((int)px[k], (int)py[k]);
            sbkt[pos] = (unsigned char)bk[k];
        }
    }
    __syncthreads();
    int cnt = min(TA, E - tile);
    for (int i = tid; i < cnt; i += 256) {
        uint32 b = sbkt[i];
        uint32 dst = baseg[b] + (uint32)i - lstart[b];
        binned[dst] = stage[i];
    }
}

// ---------------- pass B1: per-bucket degree count in LDS -> rowptr + dinv ----------------
__global__ void binBdeg_kernel(const int2* __restrict__ binned, const uint32* __restrict__ bbase,
                               uint32* __restrict__ rowptr, float* __restrict__ dinv,
                               int N, int E) {
    __shared__ uint32 cnt[NODES_PER_BKT];
    __shared__ uint32 ps[256];
    int b = blockIdx.x;
    int tid = threadIdx.x;
    cnt[tid] = 0;
    cnt[tid + 256] = 0;
    __syncthreads();
    uint32 start = bbase[b], end = bbase[b + 1];
    for (uint32 i = start + tid; i < end; i += 256)
        atomicAdd(&cnt[(uint32)binned[i].x >> 17], 1u);
    __syncthreads();
    uint32 c0 = cnt[2 * tid], c1 = cnt[2 * tid + 1];
    ps[tid] = c0 + c1;
    __syncthreads();
    for (int off = 1; off < 256; off <<= 1) {
        uint32 t = (tid >= off) ? ps[tid - off] : 0u;
        __syncthreads();
        ps[tid] += t;
        __syncthreads();
    }
    uint32 pexcl = ps[tid] - (c0 + c1);
    int base = b << NBSHIFT;
    int n0 = base + 2 * tid, n1 = n0 + 1;
    if (n0 < N) {
        rowptr[n0] = start + pexcl;
        dinv[n0] = c0 ? rsqrtf((float)c0) : 0.0f;
    }
    if (n1 < N) {
        rowptr[n1] = start + pexcl + c0;
        dinv[n1] = c1 ? rsqrtf((float)c1) : 0.0f;
    }
    if (b == gridDim.x - 1 && tid == 0) rowptr[N] = (uint32)E;
}

// ---------------- pass B2: per-bucket sort + lap; pairs.x = col<<7 (byte offset) ----------------
__global__ void binBsort_kernel(const int2* __restrict__ binned, const uint32* __restrict__ bbase,
                                const uint32* __restrict__ rowptr, const float* __restrict__ dinv,
                                int2* __restrict__ pairs, int N) {
    __shared__ uint32 lcur[NODES_PER_BKT];
    __shared__ float ldin[NODES_PER_BKT];
    int b = blockIdx.x;
    int tid = threadIdx.x;
    int base = b << NBSHIFT;
    uint32 start = bbase[b], end = bbase[b + 1];
    for (int t = tid; t < NODES_PER_BKT; t += 256) {
        int node = base + t;
        lcur[t] = (node < N) ? (rowptr[node] - start) : 0u;
        ldin[t] = (node < N) ? dinv[node] : 0.0f;
    }
    __syncthreads();
    for (uint32 i = start + tid; i < end; i += 256) {
        int2 rec = binned[i];
        uint32 x = (uint32)rec.x;
        uint32 rl = x >> 17;
        uint32 c = x & 0x1FFFFu;
        float lap = -ldin[rl] * __int_as_float(rec.y) * dinv[c];
        uint32 pos = atomicAdd(&lcur[rl], 1u);
        pairs[start + pos] = make_int2((int)(c << 7), __float_as_int(lap));
    }
}

// ---------------- CSR SpMM v4: 16 lanes/edge, uint2 gathers, 4 edges per wave-instruction ----------------
__global__ void spmm4_kernel(const uint32* __restrict__ rowptr, const int2* __restrict__ pairs,
                             const char* __restrict__ hb, const uint2* __restrict__ prev,
                             uint2* __restrict__ out, float scale, int N) {
    int n = blockIdx.x * 4 + (threadIdx.x >> 6);
    if (n >= N) return;
    int lane = threadIdx.x & 63;
    int q = lane >> 4;
    int sub = lane & 15;
    int off = sub * 8;
    uint32 j = rowptr[n];
    uint32 end = rowptr[n + 1];
    float a0 = 0.f, a1 = 0.f, a2 = 0.f, a3 = 0.f;

    for (; j + 8 <= end; j += 8) {
        int2 m0 = pairs[j + q];
        int2 m1 = pairs[j + 4 + q];
        uint2 h0 = *(const uint2*)(hb + (uint32)m0.x + off);
        uint2 h1 = *(const uint2*)(hb + (uint32)m1.x + off);
        float l0 = __int_as_float(m0.y);
        float l1 = __int_as_float(m1.y);
        a0 += l0 * __uint_as_float(h0.x << 16);
        a1 += l0 * __uint_as_float(h0.x & 0xFFFF0000u);
        a2 += l0 * __uint_as_float(h0.y << 16);
        a3 += l0 * __uint_as_float(h0.y & 0xFFFF0000u);
        a0 += l1 * __uint_as_float(h1.x << 16);
        a1 += l1 * __uint_as_float(h1.x & 0xFFFF0000u);
        a2 += l1 * __uint_as_float(h1.y << 16);
        a3 += l1 * __uint_as_float(h1.y & 0xFFFF0000u);
    }
    for (; j < end; j += 4) {
        uint32 idx = j + q;
        bool act = idx < end;
        uint32 ci = act ? idx : (end - 1);
        int2 m = pairs[ci];
        float l = act ? __int_as_float(m.y) : 0.0f;
        uint2 h0 = *(const uint2*)(hb + (uint32)m.x + off);
        a0 += l * __uint_as_float(h0.x << 16);
        a1 += l * __uint_as_float(h0.x & 0xFFFF0000u);
        a2 += l * __uint_as_float(h0.y << 16);
        a3 += l * __uint_as_float(h0.y & 0xFFFF0000u);
    }
    a0 += __shfl_xor(a0, 16); a0 += __shfl_xor(a0, 32);
    a1 += __shfl_xor(a1, 16); a1 += __shfl_xor(a1, 32);
    a2 += __shfl_xor(a2, 16); a2 += __shfl_xor(a2, 32);
    a3 += __shfl_xor(a3, 16); a3 += __shfl_xor(a3, 32);

    if (q == 0) {
        float r0 = scale * a0, r1 = scale * a1, r2 = scale * a2, r3 = scale * a3;
        size_t slot = (size_t)n * 16 + sub;
        if (prev) {
            uint2 pv = prev[slot];
            r0 -= __uint_as_float(pv.x << 16);
            r1 -= __uint_as_float(pv.x & 0xFFFF0000u);
            r2 -= __uint_as_float(pv.y << 16);
            r3 -= __uint_as_float(pv.y & 0xFFFF0000u);
        }
        uint2 pack;
        pack.x = f2bf_u(r0) | (f2bf_u(r1) << 16);
        pack.y = f2bf_u(r2) | (f2bf_u(r3) << 16);
        out[slot] = pack;
    }
}

// ---------------- gemm: out[n,:] = (bias or out) + sum_k bf16 h_k[n,:] @ W_k ----------------
__global__ void gemm_acc_bf16(const ushort16* __restrict__ h0, const ushort16* __restrict__ h1,
                              const float* __restrict__ W, const float* __restrict__ bias,
                              float* __restrict__ out, int N, int nk, int accumulate) {
    __shared__ float Ws[2 * D * D];
    int tid = threadIdx.x;
    int nload = nk * D * D;
    for (int i = tid * 4; i < nload; i += BLK * 4)
        *(float4*)&Ws[i] = *(const float4*)&W[i];
    __syncthreads();

    int n = blockIdx.x * 16 + (tid >> 4);
    if (n >= N) return;
    int c = (tid & 15) * 4;

    float4 acc;
    if (accumulate) {
        acc = *(float4*)&out[(size_t)n * D + c];
    } else {
        acc = make_float4(bias[c], bias[c + 1], bias[c + 2], bias[c + 3]);
    }

    const ushort16* hs[2] = { h0, h1 };
    for (int k = 0; k < nk; ++k) {
        const ushort16* h = hs[k] + (size_t)n * D;
        const float* Wk = &Ws[k * D * D];
        #pragma unroll
        for (int i4 = 0; i4 < 16; ++i4) {
            uint2 u = *(const uint2*)&h[i4 * 4];
            float f0 = __uint_as_float(u.x << 16);
            float f1 = __uint_as_float(u.x & 0xFFFF0000u);
            float f2 = __uint_as_float(u.y << 16);
            float f3 = __uint_as_float(u.y & 0xFFFF0000u);
            float fv[4] = { f0, f1, f2, f3 };
            #pragma unroll
            for (int u2 = 0; u2 < 4; ++u2) {
                float4 wv = *(const float4*)&Wk[(i4 * 4 + u2) * D + c];
                acc.x += fv[u2] * wv.x;
                acc.y += fv[u2] * wv.y;
                acc.z += fv[u2] * wv.z;
                acc.w += fv[u2] * wv.w;
            }
        }
    }
    *(float4*)&out[(size_t)n * D + c] = acc;
}

extern "C" void kernel_launch(void* const* d_in, const int* in_sizes, int n_in,
                              void* d_out, int out_size, void* d_ws, size_t ws_size,
                              hipStream_t stream) {
    const float* x    = (const float*)d_in[0];
    const int*   ei   = (const int*)d_in[1];
    const float* attr = (const float*)d_in[2];
    const float* W    = (const float*)d_in[3];   // [4,64,64]
    const float* bias = (const float*)d_in[4];   // [64]
    float* out = (float*)d_out;

    const int N = in_sizes[0] / D;
    const int E = in_sizes[1] / 2;
    const int* row = ei;        // edge_index[0]
    const int* col = ei + E;    // edge_index[1]
    const int NB = (N + NODES_PER_BKT - 1) >> NBSHIFT;

    // workspace layout — 8B-aligned arrays first
    char* p = (char*)d_ws;
    int2*     pairs   = (int2*)p;                p += (size_t)E * 8;
    uint2*    xb      = (uint2*)p;               p += (size_t)N * D * 2;
    uint2*    T1      = (uint2*)p;               p += (size_t)N * D * 2;
    uint2*    T2      = (uint2*)p;               p += (size_t)N * D * 2;
    uint32*   rowptr  = (uint32*)p;              p += (size_t)(N + 1) * 4;
    uint32*   bcount  = (uint32*)p;              p += 256 * 4;
    uint32*   gcursor = (uint32*)p;              p += 256 * 4;
    uint32*   bbase   = (uint32*)p;              p += 257 * 4;
    float*    dinv    = (float*)p;               /* p += N*4 */
    // binned aliases T2: consumed by binBdeg/binBsort before spmm writes T2
    int2*     binned  = (int2*)T2;

    const int gSp = (N + 3) / 4;
    const int gGe = (N + 15) / 16;
    const int gTile = (E + TA - 1) / TA;
    const int gCvt = ((N * D / 4) + BLK - 1) / BLK;

    // ---- build CSR (bucketed counting sort, no N-wide atomics) + dinv + bf16 x ----
    hipMemsetAsync(bcount, 0, 256 * 4, stream);
    cvt_kernel<<<gCvt, BLK, 0, stream>>>(x, xb, N * D / 4);
    hist_kernel<<<gTile, 256, 0, stream>>>(row, bcount, E);
    scan256_kernel<<<1, 256, 0, stream>>>(bcount, gcursor, bbase, E);
    binA_kernel<<<gTile, 256, 0, stream>>>(row, col, attr, gcursor, binned, E);
    binBdeg_kernel<<<NB, 256, 0, stream>>>(binned, bbase, rowptr, dinv, N, E);
    binBsort_kernel<<<NB, 256, 0, stream>>>(binned, bbase, rowptr, dinv, pairs, N);

    // ---- Chebyshev recurrence (bf16 storage, fp32 math) ----
    // T1 = spmm(xb)
    spmm4_kernel<<<gSp, BLK, 0, stream>>>(rowptr, pairs, (const char*)xb, nullptr, T1, 1.0f, N);
    // out = bias + x@W0 + T1@W1
    gemm_acc_bf16<<<gGe, BLK, 0, stream>>>((const ushort16*)xb, (const ushort16*)T1, W, bias, out, N, 2, 0);
    // T2 = 2*spmm(T1) - x     (overwrites binned — already consumed)
    spmm4_kernel<<<gSp, BLK, 0, stream>>>(rowptr, pairs, (const char*)T1, xb, T2, 2.0f, N);
    // T1' = 2*spmm(T2) - T1   (in place: reads prev slot before writing it)
    spmm4_kernel<<<gSp, BLK, 0, stream>>>(rowptr, pairs, (const char*)T2, T1, T1, 2.0f, N);
    // out += T2@W2 + T1'@W3
    gemm_acc_bf16<<<gGe, BLK, 0, stream>>>((const ushort16*)T2, (const ushort16*)T1, W + 2 * D * D, nullptr, out, N, 2, 1);
}

// Round 8
// 373.237 us; speedup vs baseline: 11.6626x; 1.0385x over previous
//
#include <hip/hip_runtime.h>

#define D 64
#define BLK 256

#define NBSHIFT 9
#define NODES_PER_BKT 512              // bucket = row >> 9; NB <= 256 for N <= 131072
#define TA 4096                        // edges per binA tile

typedef unsigned int uint32;
typedef unsigned short ushort16;

// ---- bf16 helpers (RTNE) ----
__device__ inline uint32 f2bf_u(float f) {
    uint32 u = __float_as_uint(f);
    u += 0x7FFFu + ((u >> 16) & 1u);
    return u >> 16;
}

// ---------------- x (fp32) -> xb (bf16), vectorized ----------------
__global__ void cvt_kernel(const float* __restrict__ x, uint2* __restrict__ xb, int n4) {
    int i = blockIdx.x * BLK + threadIdx.x;
    if (i < n4) {
        float4 v = ((const float4*)x)[i];
        uint2 pack;
        pack.x = f2bf_u(v.x) | (f2bf_u(v.y) << 16);
        pack.y = f2bf_u(v.z) | (f2bf_u(v.w) << 16);
        xb[i] = pack;
    }
}

// ---------------- bucket histogram: LDS-staged, 256 global atomics per block ----------------
__global__ void hist_kernel(const int* __restrict__ row, uint32* __restrict__ bcount, int E) {
    __shared__ uint32 h[256];
    int tid = threadIdx.x;
    h[tid] = 0;
    __syncthreads();
    int base = blockIdx.x * TA;
    int end = min(base + TA, E);
    for (int e = base + tid; e < end; e += 256)
        atomicAdd(&h[(uint32)row[e] >> NBSHIFT], 1u);
    __syncthreads();
    if (h[tid]) atomicAdd(&bcount[tid], h[tid]);
}

// ---------------- scan of 256 bucket counts -> gcursor (mutable) + bbase (stable) ----------------
__global__ void scan256_kernel(const uint32* __restrict__ bcount, uint32* __restrict__ gcursor,
                               uint32* __restrict__ bbase, int E) {
    __shared__ uint32 s[256];
    int tid = threadIdx.x;
    uint32 v = bcount[tid];
    s[tid] = v;
    __syncthreads();
    for (int off = 1; off < 256; off <<= 1) {
        uint32 t = (tid >= off) ? s[tid - off] : 0u;
        __syncthreads();
        s[tid] += t;
        __syncthreads();
    }
    uint32 excl = s[tid] - v;
    gcursor[tid] = excl;
    bbase[tid] = excl;
    if (tid == 255) bbase[256] = (uint32)E;
}

// ---------------- pass A: bin (rowlocal<<17|col, attr) by bucket, LDS-staged run writes ----------------
__global__ void binA_kernel(const int* __restrict__ row, const int* __restrict__ col,
                            const float* __restrict__ attr,
                            uint32* __restrict__ gcursor, int2* __restrict__ binned, int E) {
    __shared__ uint32 hist[256], baseg[256], lstart[256], lcur[256];
    __shared__ int2 stage[TA];
    __shared__ unsigned char sbkt[TA];
    int tid = threadIdx.x;
    int tile = blockIdx.x * TA;
    hist[tid] = 0;
    __syncthreads();

    uint32 px[16], py[16], bk[16];
    #pragma unroll
    for (int k = 0; k < 16; ++k) {
        int e = tile + k * 256 + tid;
        bk[k] = 0xFFFFFFFFu;
        if (e < E) {
            int r = row[e], c = col[e];
            uint32 b = (uint32)r >> NBSHIFT;
            bk[k] = b;
            px[k] = ((uint32)(r & (NODES_PER_BKT - 1)) << 17) | (uint32)c;
            py[k] = __float_as_uint(attr[e]);
            atomicAdd(&hist[b], 1u);
        }
    }
    __syncthreads();
    lcur[tid] = hist[tid];
    __syncthreads();
    for (int off = 1; off < 256; off <<= 1) {
        uint32 t = (tid >= off) ? lcur[tid - off] : 0u;
        __syncthreads();
        lcur[tid] += t;
        __syncthreads();
    }
    lstart[tid] = lcur[tid] - hist[tid];
    if (hist[tid] > 0) baseg[tid] = atomicAdd(&gcursor[tid], hist[tid]);
    lcur[tid] = lstart[tid];
    __syncthreads();
    #pragma unroll
    for (int k = 0; k < 16; ++k) {
        if (bk[k] != 0xFFFFFFFFu) {
            uint32 pos = atomicAdd(&lcur[bk[k]], 1u);
            stage[pos] = make_int2((int)px[k], (int)py[k]);
            sbkt[pos] = (unsigned char)bk[k];
        }
    }
    __syncthreads();
    int cnt = min(TA, E - tile);
    for (int i = tid; i < cnt; i += 256) {
        uint32 b = sbkt[i];
        uint32 dst = baseg[b] + (uint32)i - lstart[b];
        binned[dst] = stage[i];
    }
}

// ---------------- pass B1: per-bucket degree count in LDS -> rowptr + dinv ----------------
__global__ void binBdeg_kernel(const int2* __restrict__ binned, const uint32* __restrict__ bbase,
                               uint32* __restrict__ rowptr, float* __restrict__ dinv,
                               int N, int E) {
    __shared__ uint32 cnt[NODES_PER_BKT];
    __shared__ uint32 ps[256];
    int b = blockIdx.x;
    int tid = threadIdx.x;
    cnt[tid] = 0;
    cnt[tid + 256] = 0;
    __syncthreads();
    uint32 start = bbase[b], end = bbase[b + 1];
    for (uint32 i = start + tid; i < end; i += 256)
        atomicAdd(&cnt[(uint32)binned[i].x >> 17], 1u);
    __syncthreads();
    uint32 c0 = cnt[2 * tid], c1 = cnt[2 * tid + 1];
    ps[tid] = c0 + c1;
    __syncthreads();
    for (int off = 1; off < 256; off <<= 1) {
        uint32 t = (tid >= off) ? ps[tid - off] : 0u;
        __syncthreads();
        ps[tid] += t;
        __syncthreads();
    }
    uint32 pexcl = ps[tid] - (c0 + c1);
    int base = b << NBSHIFT;
    int n0 = base + 2 * tid, n1 = n0 + 1;
    if (n0 < N) {
        rowptr[n0] = start + pexcl;
        dinv[n0] = c0 ? rsqrtf((float)c0) : 0.0f;
    }
    if (n1 < N) {
        rowptr[n1] = start + pexcl + c0;
        dinv[n1] = c1 ? rsqrtf((float)c1) : 0.0f;
    }
    if (b == gridDim.x - 1 && tid == 0) rowptr[N] = (uint32)E;
}

// ---------------- pass B2: per-bucket sort + lap; pairs.x = col<<7 (byte offset) ----------------
__global__ void binBsort_kernel(const int2* __restrict__ binned, const uint32* __restrict__ bbase,
                                const uint32* __restrict__ rowptr, const float* __restrict__ dinv,
                                int2* __restrict__ pairs, int N) {
    __shared__ uint32 lcur[NODES_PER_BKT];
    __shared__ float ldin[NODES_PER_BKT];
    int b = blockIdx.x;
    int tid = threadIdx.x;
    int base = b << NBSHIFT;
    uint32 start = bbase[b], end = bbase[b + 1];
    for (int t = tid; t < NODES_PER_BKT; t += 256) {
        int node = base + t;
        lcur[t] = (node < N) ? (rowptr[node] - start) : 0u;
        ldin[t] = (node < N) ? dinv[node] : 0.0f;
    }
    __syncthreads();
    for (uint32 i = start + tid; i < end; i += 256) {
        int2 rec = binned[i];
        uint32 x = (uint32)rec.x;
        uint32 rl = x >> 17;
        uint32 c = x & 0x1FFFFu;
        float lap = -ldin[rl] * __int_as_float(rec.y) * dinv[c];
        uint32 pos = atomicAdd(&lcur[rl], 1u);
        pairs[start + pos] = make_int2((int)(c << 7), __float_as_int(lap));
    }
}

// ---------------- CSR SpMM v5: 8 lanes/edge, uint4 (16B) gathers, 8 edges per instruction ----------------
// out[n,:] = bf16( scale * sum_j lap[j]*h[col[j],:] - prev[n,:] ); one wave per node.
__global__ void spmm8_kernel(const uint32* __restrict__ rowptr, const int2* __restrict__ pairs,
                             const char* __restrict__ hb, const uint4* __restrict__ prev,
                             uint4* __restrict__ out, float scale, int N) {
    int n = blockIdx.x * 4 + (threadIdx.x >> 6);
    if (n >= N) return;
    int lane = threadIdx.x & 63;
    int q = lane >> 3;          // octet: which of 8 concurrent edges
    int sub = lane & 7;         // 8 bf16 columns per lane: [sub*8, sub*8+8)
    int off = sub * 16;         // byte offset within a 128B row
    uint32 j = rowptr[n];
    uint32 end = rowptr[n + 1];
    float a[8];
    #pragma unroll
    for (int i = 0; i < 8; ++i) a[i] = 0.0f;

    // main: 16 edges per iter (two octets), 2 meta + 2 gathers in flight
    for (; j + 16 <= end; j += 16) {
        int2 m0 = pairs[j + q];
        int2 m1 = pairs[j + 8 + q];
        uint4 h0 = *(const uint4*)(hb + (uint32)m0.x + off);
        uint4 h1 = *(const uint4*)(hb + (uint32)m1.x + off);
        float l0 = __int_as_float(m0.y);
        float l1 = __int_as_float(m1.y);
        a[0] += l0 * __uint_as_float(h0.x << 16);
        a[1] += l0 * __uint_as_float(h0.x & 0xFFFF0000u);
        a[2] += l0 * __uint_as_float(h0.y << 16);
        a[3] += l0 * __uint_as_float(h0.y & 0xFFFF0000u);
        a[4] += l0 * __uint_as_float(h0.z << 16);
        a[5] += l0 * __uint_as_float(h0.z & 0xFFFF0000u);
        a[6] += l0 * __uint_as_float(h0.w << 16);
        a[7] += l0 * __uint_as_float(h0.w & 0xFFFF0000u);
        a[0] += l1 * __uint_as_float(h1.x << 16);
        a[1] += l1 * __uint_as_float(h1.x & 0xFFFF0000u);
        a[2] += l1 * __uint_as_float(h1.y << 16);
        a[3] += l1 * __uint_as_float(h1.y & 0xFFFF0000u);
        a[4] += l1 * __uint_as_float(h1.z << 16);
        a[5] += l1 * __uint_as_float(h1.z & 0xFFFF0000u);
        a[6] += l1 * __uint_as_float(h1.w << 16);
        a[7] += l1 * __uint_as_float(h1.w & 0xFFFF0000u);
    }
    // tail: octets with masking (clamp index; end-1 >= j valid when loop entered)
    for (; j < end; j += 8) {
        uint32 idx = j + q;
        bool act = idx < end;
        uint32 ci = act ? idx : (end - 1);
        int2 m = pairs[ci];
        float l = act ? __int_as_float(m.y) : 0.0f;
        uint4 h0 = *(const uint4*)(hb + (uint32)m.x + off);
        a[0] += l * __uint_as_float(h0.x << 16);
        a[1] += l * __uint_as_float(h0.x & 0xFFFF0000u);
        a[2] += l * __uint_as_float(h0.y << 16);
        a[3] += l * __uint_as_float(h0.y & 0xFFFF0000u);
        a[4] += l * __uint_as_float(h0.z << 16);
        a[5] += l * __uint_as_float(h0.z & 0xFFFF0000u);
        a[6] += l * __uint_as_float(h0.w << 16);
        a[7] += l * __uint_as_float(h0.w & 0xFFFF0000u);
    }
    // reduce across octets (same sub -> same columns)
    #pragma unroll
    for (int i = 0; i < 8; ++i) {
        a[i] += __shfl_xor(a[i], 8);
        a[i] += __shfl_xor(a[i], 16);
        a[i] += __shfl_xor(a[i], 32);
    }

    if (q == 0) {              // lanes 0..7, sub = lane
        float r[8];
        #pragma unroll
        for (int i = 0; i < 8; ++i) r[i] = scale * a[i];
        size_t slot = (size_t)n * 8 + sub;   // uint4 index: 8 per 128B row
        if (prev) {
            uint4 pv = prev[slot];
            r[0] -= __uint_as_float(pv.x << 16);
            r[1] -= __uint_as_float(pv.x & 0xFFFF0000u);
            r[2] -= __uint_as_float(pv.y << 16);
            r[3] -= __uint_as_float(pv.y & 0xFFFF0000u);
            r[4] -= __uint_as_float(pv.z << 16);
            r[5] -= __uint_as_float(pv.z & 0xFFFF0000u);
            r[6] -= __uint_as_float(pv.w << 16);
            r[7] -= __uint_as_float(pv.w & 0xFFFF0000u);
        }
        uint4 pack;
        pack.x = f2bf_u(r[0]) | (f2bf_u(r[1]) << 16);
        pack.y = f2bf_u(r[2]) | (f2bf_u(r[3]) << 16);
        pack.z = f2bf_u(r[4]) | (f2bf_u(r[5]) << 16);
        pack.w = f2bf_u(r[6]) | (f2bf_u(r[7]) << 16);
        out[slot] = pack;
    }
}

// ---------------- gemm: out[n,:] = (bias or out) + sum_k bf16 h_k[n,:] @ W_k ----------------
__global__ void gemm_acc_bf16(const ushort16* __restrict__ h0, const ushort16* __restrict__ h1,
                              const float* __restrict__ W, const float* __restrict__ bias,
                              float* __restrict__ out, int N, int nk, int accumulate) {
    __shared__ float Ws[2 * D * D];
    int tid = threadIdx.x;
    int nload = nk * D * D;
    for (int i = tid * 4; i < nload; i += BLK * 4)
        *(float4*)&Ws[i] = *(const float4*)&W[i];
    __syncthreads();

    int n = blockIdx.x * 16 + (tid >> 4);
    if (n >= N) return;
    int c = (tid & 15) * 4;

    float4 acc;
    if (accumulate) {
        acc = *(float4*)&out[(size_t)n * D + c];
    } else {
        acc = make_float4(bias[c], bias[c + 1], bias[c + 2], bias[c + 3]);
    }

    const ushort16* hs[2] = { h0, h1 };
    for (int k = 0; k < nk; ++k) {
        const ushort16* h = hs[k] + (size_t)n * D;
        const float* Wk = &Ws[k * D * D];
        #pragma unroll
        for (int i4 = 0; i4 < 16; ++i4) {
            uint2 u = *(const uint2*)&h[i4 * 4];
            float f0 = __uint_as_float(u.x << 16);
            float f1 = __uint_as_float(u.x & 0xFFFF0000u);
            float f2 = __uint_as_float(u.y << 16);
            float f3 = __uint_as_float(u.y & 0xFFFF0000u);
            float fv[4] = { f0, f1, f2, f3 };
            #pragma unroll
            for (int u2 = 0; u2 < 4; ++u2) {
                float4 wv = *(const float4*)&Wk[(i4 * 4 + u2) * D + c];
                acc.x += fv[u2] * wv.x;
                acc.y += fv[u2] * wv.y;
                acc.z += fv[u2] * wv.z;
                acc.w += fv[u2] * wv.w;
            }
        }
    }
    *(float4*)&out[(size_t)n * D + c] = acc;
}

extern "C" void kernel_launch(void* const* d_in, const int* in_sizes, int n_in,
                              void* d_out, int out_size, void* d_ws, size_t ws_size,
                              hipStream_t stream) {
    const float* x    = (const float*)d_in[0];
    const int*   ei   = (const int*)d_in[1];
    const float* attr = (const float*)d_in[2];
    const float* W    = (const float*)d_in[3];   // [4,64,64]
    const float* bias = (const float*)d_in[4];   // [64]
    float* out = (float*)d_out;

    const int N = in_sizes[0] / D;
    const int E = in_sizes[1] / 2;
    const int* row = ei;        // edge_index[0]
    const int* col = ei + E;    // edge_index[1]
    const int NB = (N + NODES_PER_BKT - 1) >> NBSHIFT;

    // workspace layout — 16B-aligned arrays first
    char* p = (char*)d_ws;
    int2*     pairs   = (int2*)p;                p += (size_t)E * 8;
    uint2*    xb      = (uint2*)p;               p += (size_t)N * D * 2;
    uint2*    T1      = (uint2*)p;               p += (size_t)N * D * 2;
    uint2*    T2      = (uint2*)p;               p += (size_t)N * D * 2;
    uint32*   rowptr  = (uint32*)p;              p += (size_t)(N + 1) * 4;
    uint32*   bcount  = (uint32*)p;              p += 256 * 4;
    uint32*   gcursor = (uint32*)p;              p += 256 * 4;
    uint32*   bbase   = (uint32*)p;              p += 257 * 4;
    float*    dinv    = (float*)p;               /* p += N*4 */
    // binned aliases T2: consumed by binBdeg/binBsort before spmm writes T2
    int2*     binned  = (int2*)T2;

    const int gSp = (N + 3) / 4;
    const int gGe = (N + 15) / 16;
    const int gTile = (E + TA - 1) / TA;
    const int gCvt = ((N * D / 4) + BLK - 1) / BLK;

    // ---- build CSR (bucketed counting sort, no N-wide atomics) + dinv + bf16 x ----
    hipMemsetAsync(bcount, 0, 256 * 4, stream);
    cvt_kernel<<<gCvt, BLK, 0, stream>>>(x, xb, N * D / 4);
    hist_kernel<<<gTile, 256, 0, stream>>>(row, bcount, E);
    scan256_kernel<<<1, 256, 0, stream>>>(bcount, gcursor, bbase, E);
    binA_kernel<<<gTile, 256, 0, stream>>>(row, col, attr, gcursor, binned, E);
    binBdeg_kernel<<<NB, 256, 0, stream>>>(binned, bbase, rowptr, dinv, N, E);
    binBsort_kernel<<<NB, 256, 0, stream>>>(binned, bbase, rowptr, dinv, pairs, N);

    // ---- Chebyshev recurrence (bf16 storage, fp32 math) ----
    // T1 = spmm(xb)
    spmm8_kernel<<<gSp, BLK, 0, stream>>>(rowptr, pairs, (const char*)xb, nullptr, (uint4*)T1, 1.0f, N);
    // out = bias + x@W0 + T1@W1
    gemm_acc_bf16<<<gGe, BLK, 0, stream>>>((const ushort16*)xb, (const ushort16*)T1, W, bias, out, N, 2, 0);
    // T2 = 2*spmm(T1) - x     (overwrites binned — already consumed)
    spmm8_kernel<<<gSp, BLK, 0, stream>>>(rowptr, pairs, (const char*)T1, (const uint4*)xb, (uint4*)T2, 2.0f, N);
    // T1' = 2*spmm(T2) - T1   (in place: each slot read then written by one wave only)
    spmm8_kernel<<<gSp, BLK, 0, stream>>>(rowptr, pairs, (const char*)T2, (const uint4*)T1, (uint4*)T1, 2.0f, N);
    // out += T2@W2 + T1'@W3
    gemm_acc_bf16<<<gGe, BLK, 0, stream>>>((const ushort16*)T2, (const ushort16*)T1, W + 2 * D * D, nullptr, out, N, 2, 1);
}

// Round 9
// 313.448 us; speedup vs baseline: 13.8872x; 1.1907x over previous
//
#include <hip/hip_runtime.h>

#define D 64
#define BLK 256

#define NBSHIFT 9
#define NODES_PER_BKT 512              // bucket = row >> 9; NB <= 256 for N <= 131072
#define TA 4096                        // edges per binA tile

typedef unsigned int uint32;
typedef __attribute__((ext_vector_type(8))) short bf16x8;
typedef __attribute__((ext_vector_type(4))) float f32x4;

// ---- bf16 helpers (RTNE) ----
__device__ inline uint32 f2bf_u(float f) {
    uint32 u = __float_as_uint(f);
    u += 0x7FFFu + ((u >> 16) & 1u);
    return u >> 16;
}

// ---------------- x (fp32) -> xb (bf16), vectorized ----------------
__global__ void cvt_kernel(const float* __restrict__ x, uint2* __restrict__ xb, int n4) {
    int i = blockIdx.x * BLK + threadIdx.x;
    if (i < n4) {
        float4 v = ((const float4*)x)[i];
        uint2 pack;
        pack.x = f2bf_u(v.x) | (f2bf_u(v.y) << 16);
        pack.y = f2bf_u(v.z) | (f2bf_u(v.w) << 16);
        xb[i] = pack;
    }
}

// ---------------- W (fp32 [4][64][64]) -> Wf (bf16 B-fragment layout) ----------------
// Wf[(w*8 + t*2 + kh)*64 + lane] = uint4 of 8 bf16: B[k=kh*32+(lane>>4)*8+j][n=t*16+(lane&15)]
__global__ void wf_kernel(const float* __restrict__ W, uint4* __restrict__ Wf) {
    int tid = blockIdx.x * 256 + threadIdx.x;   // 0..2047
    int l = tid & 63;
    int g = tid >> 6;       // 0..31
    int kh = g & 1;
    int t = (g >> 1) & 3;
    int w = g >> 3;
    int n = t * 16 + (l & 15);
    int kbase = kh * 32 + (l >> 4) * 8;
    uint32 pk[4];
    #pragma unroll
    for (int i = 0; i < 4; ++i) {
        uint32 b0 = f2bf_u(W[(size_t)w * 4096 + (size_t)(kbase + 2 * i) * 64 + n]);
        uint32 b1 = f2bf_u(W[(size_t)w * 4096 + (size_t)(kbase + 2 * i + 1) * 64 + n]);
        pk[i] = b0 | (b1 << 16);
    }
    Wf[tid] = make_uint4(pk[0], pk[1], pk[2], pk[3]);
}

// ---------------- bucket histogram: LDS-staged, 256 global atomics per block ----------------
__global__ void hist_kernel(const int* __restrict__ row, uint32* __restrict__ bcount, int E) {
    __shared__ uint32 h[256];
    int tid = threadIdx.x;
    h[tid] = 0;
    __syncthreads();
    int base = blockIdx.x * TA;
    int end = min(base + TA, E);
    for (int e = base + tid; e < end; e += 256)
        atomicAdd(&h[(uint32)row[e] >> NBSHIFT], 1u);
    __syncthreads();
    if (h[tid]) atomicAdd(&bcount[tid], h[tid]);
}

// ---------------- scan of 256 bucket counts -> gcursor (mutable) + bbase (stable) ----------------
__global__ void scan256_kernel(const uint32* __restrict__ bcount, uint32* __restrict__ gcursor,
                               uint32* __restrict__ bbase, int E) {
    __shared__ uint32 s[256];
    int tid = threadIdx.x;
    uint32 v = bcount[tid];
    s[tid] = v;
    __syncthreads();
    for (int off = 1; off < 256; off <<= 1) {
        uint32 t = (tid >= off) ? s[tid - off] : 0u;
        __syncthreads();
        s[tid] += t;
        __syncthreads();
    }
    uint32 excl = s[tid] - v;
    gcursor[tid] = excl;
    bbase[tid] = excl;
    if (tid == 255) bbase[256] = (uint32)E;
}

// ---------------- pass A: bin (rowlocal<<17|col, attr) by bucket, LDS-staged run writes ----------------
__global__ void binA_kernel(const int* __restrict__ row, const int* __restrict__ col,
                            const float* __restrict__ attr,
                            uint32* __restrict__ gcursor, int2* __restrict__ binned, int E) {
    __shared__ uint32 hist[256], baseg[256], lstart[256], lcur[256];
    __shared__ int2 stage[TA];
    __shared__ unsigned char sbkt[TA];
    int tid = threadIdx.x;
    int tile = blockIdx.x * TA;
    hist[tid] = 0;
    __syncthreads();

    uint32 px[16], py[16], bk[16];
    #pragma unroll
    for (int k = 0; k < 16; ++k) {
        int e = tile + k * 256 + tid;
        bk[k] = 0xFFFFFFFFu;
        if (e < E) {
            int r = row[e], c = col[e];
            uint32 b = (uint32)r >> NBSHIFT;
            bk[k] = b;
            px[k] = ((uint32)(r & (NODES_PER_BKT - 1)) << 17) | (uint32)c;
            py[k] = __float_as_uint(attr[e]);
            atomicAdd(&hist[b], 1u);
        }
    }
    __syncthreads();
    lcur[tid] = hist[tid];
    __syncthreads();
    for (int off = 1; off < 256; off <<= 1) {
        uint32 t = (tid >= off) ? lcur[tid - off] : 0u;
        __syncthreads();
        lcur[tid] += t;
        __syncthreads();
    }
    lstart[tid] = lcur[tid] - hist[tid];
    if (hist[tid] > 0) baseg[tid] = atomicAdd(&gcursor[tid], hist[tid]);
    lcur[tid] = lstart[tid];
    __syncthreads();
    #pragma unroll
    for (int k = 0; k < 16; ++k) {
        if (bk[k] != 0xFFFFFFFFu) {
            uint32 pos = atomicAdd(&lcur[bk[k]], 1u);
            stage[pos] = make_int2((int)px[k], (int)py[k]);
            sbkt[pos] = (unsigned char)bk[k];
        }
    }
    __syncthreads();
    int cnt = min(TA, E - tile);
    for (int i = tid; i < cnt; i += 256) {
        uint32 b = sbkt[i];
        uint32 dst = baseg[b] + (uint32)i - lstart[b];
        binned[dst] = stage[i];
    }
}

// ---------------- pass B1: per-bucket degree count in LDS -> rowptr + dinv ----------------
__global__ void binBdeg_kernel(const int2* __restrict__ binned, const uint32* __restrict__ bbase,
                               uint32* __restrict__ rowptr, float* __restrict__ dinv,
                               int N, int E) {
    __shared__ uint32 cnt[NODES_PER_BKT];
    __shared__ uint32 ps[256];
    int b = blockIdx.x;
    int tid = threadIdx.x;
    cnt[tid] = 0;
    cnt[tid + 256] = 0;
    __syncthreads();
    uint32 start = bbase[b], end = bbase[b + 1];
    for (uint32 i = start + tid; i < end; i += 256)
        atomicAdd(&cnt[(uint32)binned[i].x >> 17], 1u);
    __syncthreads();
    uint32 c0 = cnt[2 * tid], c1 = cnt[2 * tid + 1];
    ps[tid] = c0 + c1;
    __syncthreads();
    for (int off = 1; off < 256; off <<= 1) {
        uint32 t = (tid >= off) ? ps[tid - off] : 0u;
        __syncthreads();
        ps[tid] += t;
        __syncthreads();
    }
    uint32 pexcl = ps[tid] - (c0 + c1);
    int base = b << NBSHIFT;
    int n0 = base + 2 * tid, n1 = n0 + 1;
    if (n0 < N) {
        rowptr[n0] = start + pexcl;
        dinv[n0] = c0 ? rsqrtf((float)c0) : 0.0f;
    }
    if (n1 < N) {
        rowptr[n1] = start + pexcl + c0;
        dinv[n1] = c1 ? rsqrtf((float)c1) : 0.0f;
    }
    if (b == gridDim.x - 1 && tid == 0) rowptr[N] = (uint32)E;
}

// ---------------- pass B2: per-bucket sort + lap; pairs.x = col<<7 (byte offset) ----------------
__global__ void binBsort_kernel(const int2* __restrict__ binned, const uint32* __restrict__ bbase,
                                const uint32* __restrict__ rowptr, const float* __restrict__ dinv,
                                int2* __restrict__ pairs, int N) {
    __shared__ uint32 lcur[NODES_PER_BKT];
    __shared__ float ldin[NODES_PER_BKT];
    int b = blockIdx.x;
    int tid = threadIdx.x;
    int base = b << NBSHIFT;
    uint32 start = bbase[b], end = bbase[b + 1];
    for (int t = tid; t < NODES_PER_BKT; t += 256) {
        int node = base + t;
        lcur[t] = (node < N) ? (rowptr[node] - start) : 0u;
        ldin[t] = (node < N) ? dinv[node] : 0.0f;
    }
    __syncthreads();
    for (uint32 i = start + tid; i < end; i += 256) {
        int2 rec = binned[i];
        uint32 x = (uint32)rec.x;
        uint32 rl = x >> 17;
        uint32 c = x & 0x1FFFFu;
        float lap = -ldin[rl] * __int_as_float(rec.y) * dinv[c];
        uint32 pos = atomicAdd(&lcur[rl], 1u);
        pairs[start + pos] = make_int2((int)(c << 7), __float_as_int(lap));
    }
}

// ---------------- CSR SpMM v5: 8 lanes/edge, uint4 (16B) gathers ----------------
__global__ void spmm8_kernel(const uint32* __restrict__ rowptr, const int2* __restrict__ pairs,
                             const char* __restrict__ hb, const uint4* __restrict__ prev,
                             uint4* __restrict__ out, float scale, int N) {
    int n = blockIdx.x * 4 + (threadIdx.x >> 6);
    if (n >= N) return;
    int lane = threadIdx.x & 63;
    int q = lane >> 3;
    int sub = lane & 7;
    int off = sub * 16;
    uint32 j = rowptr[n];
    uint32 end = rowptr[n + 1];
    float a[8];
    #pragma unroll
    for (int i = 0; i < 8; ++i) a[i] = 0.0f;

    for (; j + 16 <= end; j += 16) {
        int2 m0 = pairs[j + q];
        int2 m1 = pairs[j + 8 + q];
        uint4 h0 = *(const uint4*)(hb + (uint32)m0.x + off);
        uint4 h1 = *(const uint4*)(hb + (uint32)m1.x + off);
        float l0 = __int_as_float(m0.y);
        float l1 = __int_as_float(m1.y);
        a[0] += l0 * __uint_as_float(h0.x << 16);
        a[1] += l0 * __uint_as_float(h0.x & 0xFFFF0000u);
        a[2] += l0 * __uint_as_float(h0.y << 16);
        a[3] += l0 * __uint_as_float(h0.y & 0xFFFF0000u);
        a[4] += l0 * __uint_as_float(h0.z << 16);
        a[5] += l0 * __uint_as_float(h0.z & 0xFFFF0000u);
        a[6] += l0 * __uint_as_float(h0.w << 16);
        a[7] += l0 * __uint_as_float(h0.w & 0xFFFF0000u);
        a[0] += l1 * __uint_as_float(h1.x << 16);
        a[1] += l1 * __uint_as_float(h1.x & 0xFFFF0000u);
        a[2] += l1 * __uint_as_float(h1.y << 16);
        a[3] += l1 * __uint_as_float(h1.y & 0xFFFF0000u);
        a[4] += l1 * __uint_as_float(h1.z << 16);
        a[5] += l1 * __uint_as_float(h1.z & 0xFFFF0000u);
        a[6] += l1 * __uint_as_float(h1.w << 16);
        a[7] += l1 * __uint_as_float(h1.w & 0xFFFF0000u);
    }
    for (; j < end; j += 8) {
        uint32 idx = j + q;
        bool act = idx < end;
        uint32 ci = act ? idx : (end - 1);
        int2 m = pairs[ci];
        float l = act ? __int_as_float(m.y) : 0.0f;
        uint4 h0 = *(const uint4*)(hb + (uint32)m.x + off);
        a[0] += l * __uint_as_float(h0.x << 16);
        a[1] += l * __uint_as_float(h0.x & 0xFFFF0000u);
        a[2] += l * __uint_as_float(h0.y << 16);
        a[3] += l * __uint_as_float(h0.y & 0xFFFF0000u);
        a[4] += l * __uint_as_float(h0.z << 16);
        a[5] += l * __uint_as_float(h0.z & 0xFFFF0000u);
        a[6] += l * __uint_as_float(h0.w << 16);
        a[7] += l * __uint_as_float(h0.w & 0xFFFF0000u);
    }
    #pragma unroll
    for (int i = 0; i < 8; ++i) {
        a[i] += __shfl_xor(a[i], 8);
        a[i] += __shfl_xor(a[i], 16);
        a[i] += __shfl_xor(a[i], 32);
    }

    if (q == 0) {
        float r[8];
        #pragma unroll
        for (int i = 0; i < 8; ++i) r[i] = scale * a[i];
        size_t slot = (size_t)n * 8 + sub;
        if (prev) {
            uint4 pv = prev[slot];
            r[0] -= __uint_as_float(pv.x << 16);
            r[1] -= __uint_as_float(pv.x & 0xFFFF0000u);
            r[2] -= __uint_as_float(pv.y << 16);
            r[3] -= __uint_as_float(pv.y & 0xFFFF0000u);
            r[4] -= __uint_as_float(pv.z << 16);
            r[5] -= __uint_as_float(pv.z & 0xFFFF0000u);
            r[6] -= __uint_as_float(pv.w << 16);
            r[7] -= __uint_as_float(pv.w & 0xFFFF0000u);
        }
        uint4 pack;
        pack.x = f2bf_u(r[0]) | (f2bf_u(r[1]) << 16);
        pack.y = f2bf_u(r[2]) | (f2bf_u(r[3]) << 16);
        pack.z = f2bf_u(r[4]) | (f2bf_u(r[5]) << 16);
        pack.w = f2bf_u(r[6]) | (f2bf_u(r[7]) << 16);
        out[slot] = pack;
    }
}

// ---------------- fused MFMA GEMM: out = bias + x@W0 + T1@W1 + T2@W2 + T3@W3 ----------------
// One wave per 16 rows; 4 acc tiles (16 cols each); 32 mfma_f32_16x16x32_bf16.
// A-frag: lane holds h[m0+(lane&15)][kh*32+quad*8 .. +8] = one uint4.
// B-frag: prepacked Wf (see wf_kernel). C/D: col=lane&15, row=quad*4+reg.
__global__ void gemm_mfma(const uint4* __restrict__ h0, const uint4* __restrict__ h1,
                          const uint4* __restrict__ h2, const uint4* __restrict__ h3,
                          const uint4* __restrict__ Wf, const float* __restrict__ bias,
                          float* __restrict__ out, int N) {
    int tid = threadIdx.x;
    int wave = tid >> 6;
    int lane = tid & 63;
    int quad = lane >> 4;
    int lo = lane & 15;
    int m0 = blockIdx.x * 64 + wave * 16;
    int mrow = m0 + lo;
    int mclamp = min(mrow, N - 1);

    f32x4 acc[4] = {{0.f,0.f,0.f,0.f},{0.f,0.f,0.f,0.f},{0.f,0.f,0.f,0.f},{0.f,0.f,0.f,0.f}};
    const uint4* hs[4] = { h0, h1, h2, h3 };
    #pragma unroll
    for (int w = 0; w < 4; ++w) {
        union { uint4 u; bf16x8 v; } a0, a1;
        a0.u = hs[w][(size_t)mclamp * 8 + quad];       // kh = 0
        a1.u = hs[w][(size_t)mclamp * 8 + 4 + quad];   // kh = 1
        #pragma unroll
        for (int t = 0; t < 4; ++t) {
            union { uint4 u; bf16x8 v; } b0, b1;
            b0.u = Wf[(w * 8 + t * 2 + 0) * 64 + lane];
            b1.u = Wf[(w * 8 + t * 2 + 1) * 64 + lane];
            acc[t] = __builtin_amdgcn_mfma_f32_16x16x32_bf16(a0.v, b0.v, acc[t], 0, 0, 0);
            acc[t] = __builtin_amdgcn_mfma_f32_16x16x32_bf16(a1.v, b1.v, acc[t], 0, 0, 0);
        }
    }
    #pragma unroll
    for (int t = 0; t < 4; ++t) {
        int col = t * 16 + lo;
        float bv = bias[col];
        #pragma unroll
        for (int r = 0; r < 4; ++r) {
            int rowi = m0 + quad * 4 + r;
            if (rowi < N) out[(size_t)rowi * 64 + col] = acc[t][r] + bv;
        }
    }
}

extern "C" void kernel_launch(void* const* d_in, const int* in_sizes, int n_in,
                              void* d_out, int out_size, void* d_ws, size_t ws_size,
                              hipStream_t stream) {
    const float* x    = (const float*)d_in[0];
    const int*   ei   = (const int*)d_in[1];
    const float* attr = (const float*)d_in[2];
    const float* W    = (const float*)d_in[3];   // [4,64,64]
    const float* bias = (const float*)d_in[4];   // [64]
    float* out = (float*)d_out;

    const int N = in_sizes[0] / D;
    const int E = in_sizes[1] / 2;
    const int* row = ei;        // edge_index[0]
    const int* col = ei + E;    // edge_index[1]
    const int NB = (N + NODES_PER_BKT - 1) >> NBSHIFT;

    // workspace layout — 16B-aligned arrays first
    char* p = (char*)d_ws;
    int2*     pairs   = (int2*)p;                p += (size_t)E * 8;
    uint2*    xb      = (uint2*)p;               p += (size_t)N * D * 2;
    uint2*    T1      = (uint2*)p;               p += (size_t)N * D * 2;
    uint2*    T2      = (uint2*)p;               p += (size_t)N * D * 2;
    uint2*    T3      = (uint2*)p;               p += (size_t)N * D * 2;
    uint4*    Wf      = (uint4*)p;               p += 2048 * 16;
    uint32*   rowptr  = (uint32*)p;              p += (size_t)(N + 1) * 4;
    uint32*   bcount  = (uint32*)p;              p += 256 * 4;
    uint32*   gcursor = (uint32*)p;              p += 256 * 4;
    uint32*   bbase   = (uint32*)p;              p += 257 * 4;
    float*    dinv    = (float*)p;               /* p += N*4 */
    // binned aliases T3: consumed by binBdeg/binBsort before 3rd spmm writes T3
    int2*     binned  = (int2*)T3;

    const int gSp = (N + 3) / 4;
    const int gGm = (N + 63) / 64;
    const int gTile = (E + TA - 1) / TA;
    const int gCvt = ((N * D / 4) + BLK - 1) / BLK;

    // ---- build CSR (bucketed counting sort, no N-wide atomics) + dinv + bf16 x/W ----
    hipMemsetAsync(bcount, 0, 256 * 4, stream);
    cvt_kernel<<<gCvt, BLK, 0, stream>>>(x, xb, N * D / 4);
    wf_kernel<<<8, 256, 0, stream>>>(W, Wf);
    hist_kernel<<<gTile, 256, 0, stream>>>(row, bcount, E);
    scan256_kernel<<<1, 256, 0, stream>>>(bcount, gcursor, bbase, E);
    binA_kernel<<<gTile, 256, 0, stream>>>(row, col, attr, gcursor, binned, E);
    binBdeg_kernel<<<NB, 256, 0, stream>>>(binned, bbase, rowptr, dinv, N, E);
    binBsort_kernel<<<NB, 256, 0, stream>>>(binned, bbase, rowptr, dinv, pairs, N);

    // ---- Chebyshev recurrence (bf16 storage, fp32 math) ----
    // T1 = spmm(xb)
    spmm8_kernel<<<gSp, BLK, 0, stream>>>(rowptr, pairs, (const char*)xb, nullptr, (uint4*)T1, 1.0f, N);
    // T2 = 2*spmm(T1) - x
    spmm8_kernel<<<gSp, BLK, 0, stream>>>(rowptr, pairs, (const char*)T1, (const uint4*)xb, (uint4*)T2, 2.0f, N);
    // T3 = 2*spmm(T2) - T1   (binned already consumed)
    spmm8_kernel<<<gSp, BLK, 0, stream>>>(rowptr, pairs, (const char*)T2, (const uint4*)T1, (uint4*)T3, 2.0f, N);
    // out = bias + x@W0 + T1@W1 + T2@W2 + T3@W3  (single MFMA GEMM, K=4x64)
    gemm_mfma<<<gGm, BLK, 0, stream>>>((const uint4*)xb, (const uint4*)T1, (const uint4*)T2,
                                       (const uint4*)T3, Wf, bias, out, N);
}